// Round 11
// baseline (5974.432 us; speedup 1.0000x reference)
//
#include <hip/hip_runtime.h>
#include <math.h>

constexpr int SVEC = 576;    // N_CH * 64
constexpr int INF  = 2304;   // 4 * SVEC
constexpr int HID  = 256;
constexpr int OUTF = 1152;   // 2 * SVEC
constexpr int TS   = 20;
constexpr int RSL  = 104;    // slot: r[0:32] d[32:64] q[64:96] alpha[96] done[97]

// ---------- helpers ----------------------------------------------------------
__device__ __forceinline__ ushort f2bf(float f) {    // RNE f32->bf16
    union { float f; unsigned u; } a; a.f = f;
    unsigned r = a.u + 0x7fff + ((a.u >> 16) & 1);
    return (ushort)(r >> 16);
}
__device__ __forceinline__ float bf2f(ushort b) {
    union { unsigned u; float f; } a; a.u = ((unsigned)b) << 16;
    return a.f;
}

__device__ __forceinline__ void gload_lds16(const void* g, void* l) {
    __builtin_amdgcn_global_load_lds(
        (const __attribute__((address_space(1))) void*)g,
        (__attribute__((address_space(3))) void*)l, 16, 0, 0);
}

typedef short  s16x8 __attribute__((ext_vector_type(8)));
typedef float  f32x4 __attribute__((ext_vector_type(4)));

// ---------- init: Sb(bf16) = [x|p|y|z] all = [noisy, 0...] -------------------
__global__ __launch_bounds__(256) void k_init(ushort* __restrict__ Sb,
                                              const float4* __restrict__ noisy4,
                                              int tot8) {
    int i = blockIdx.x * 256 + threadIdx.x;
    if (i >= tot8) return;
    int sample = i / 288;
    int j = i - sample * 288;       // slot within sample
    int jc = j % 72;                // slot within chunk
    s16x8 o = (s16x8){0,0,0,0,0,0,0,0};
    if (jc < 8) {                   // first 64 elems = noisy
        float4 a = noisy4[sample * 16 + jc * 2];
        float4 b = noisy4[sample * 16 + jc * 2 + 1];
        ushort* u = (ushort*)&o;
        u[0]=f2bf(a.x); u[1]=f2bf(a.y); u[2]=f2bf(a.z); u[3]=f2bf(a.w);
        u[4]=f2bf(b.x); u[5]=f2bf(b.y); u[6]=f2bf(b.z); u[7]=f2bf(b.w);
    }
    *(s16x8*)&Sb[(size_t)i * 8] = o;
}

__global__ __launch_bounds__(128) void k_zero(float* __restrict__ p, int n) {
    int i = blockIdx.x * 128 + threadIdx.x;
    if (i < n) p[i] = 0.f;
}

// ---------- weight transpose + bf16 convert: Wt[n*K+k] = W[k*N+n] ------------
__global__ __launch_bounds__(256) void k_wt(const float* __restrict__ W,
                                            ushort* __restrict__ Wt,
                                            int K, int N, int total) {
    int i = blockIdx.x * 256 + threadIdx.x;
    if (i >= total) return;
    int n = i / K, k = i - n * K;
    Wt[i] = f2bf(W[(size_t)k * N + n]);
}

// ---------- elementwise FBS (in-place on bf16 Sb); 24 elems per thread -------
// No barriers before compute; 18 independent 16B loads in flight.
__global__ __launch_bounds__(256) void k_fbs(ushort* __restrict__ Sb,
                                             const ushort* __restrict__ uv,
                                             const float* __restrict__ alpha_p,
                                             float* __restrict__ redcur,
                                             float an, int tot24 /* B*24 */) {
    int i = blockIdx.x * 256 + threadIdx.x;
    float r = 0.f, d = 0.f;
    if (i < tot24) {
        int sample = i / 24;
        int j24 = (i - sample * 24) * 24;        // elem offset within chunk
        size_t sb = (size_t)sample * INF + j24;
        size_t ub = (size_t)sample * OUTF + j24;
        const float al = *alpha_p;
        s16x8 x8[3], p8[3], y8[3], z8[3], u8[3], v8[3];
        #pragma unroll
        for (int g = 0; g < 3; ++g) x8[g] = *(const s16x8*)(Sb + sb + g * 8);
        #pragma unroll
        for (int g = 0; g < 3; ++g) p8[g] = *(const s16x8*)(Sb + sb + 576 + g * 8);
        #pragma unroll
        for (int g = 0; g < 3; ++g) y8[g] = *(const s16x8*)(Sb + sb + 1152 + g * 8);
        #pragma unroll
        for (int g = 0; g < 3; ++g) z8[g] = *(const s16x8*)(Sb + sb + 1728 + g * 8);
        #pragma unroll
        for (int g = 0; g < 3; ++g) u8[g] = *(const s16x8*)(uv + ub + g * 8);
        #pragma unroll
        for (int g = 0; g < 3; ++g) v8[g] = *(const s16x8*)(uv + ub + 576 + g * 8);
        s16x8 xo[3], po[3], yo[3], zo[3];
        #pragma unroll
        for (int g = 0; g < 3; ++g) {
            const ushort* X = (const ushort*)&x8[g]; const ushort* P = (const ushort*)&p8[g];
            const ushort* Y = (const ushort*)&y8[g]; const ushort* Z = (const ushort*)&z8[g];
            const ushort* U = (const ushort*)&u8[g]; const ushort* V = (const ushort*)&v8[g];
            ushort* XO = (ushort*)&xo[g]; ushort* PO = (ushort*)&po[g];
            ushort* YO = (ushort*)&yo[g]; ushort* ZO = (ushort*)&zo[g];
            #pragma unroll
            for (int c = 0; c < 8; ++c) {
                float x = bf2f(X[c]), p = bf2f(P[c]);
                float yv = bf2f(Y[c]), zv = bf2f(Z[c]);
                float u = al * bf2f(U[c]), v = al * bf2f(V[c]);
                float y  = x + an * (yv - x) + u;
                float dz = an * (zv - p);
                float z  = x + an * (p - x) + dz + u + v;
                float zm = z - y;
                float t  = fabsf(zm) - 0.1f;
                float pr = (t > 0.f) ? copysignf(t, zm) : 0.f;
                float xn = x + (pr - z) + dz;
                XO[c] = f2bf(xn); PO[c] = f2bf(pr); YO[c] = f2bf(y); ZO[c] = f2bf(z);
                float e1 = pr - y; r += e1 * e1;
                float e2 = xn - z; d += e2 * e2;
            }
        }
        #pragma unroll
        for (int g = 0; g < 3; ++g) *(s16x8*)(Sb + sb + g * 8)        = xo[g];
        #pragma unroll
        for (int g = 0; g < 3; ++g) *(s16x8*)(Sb + sb + 576 + g * 8)  = po[g];
        #pragma unroll
        for (int g = 0; g < 3; ++g) *(s16x8*)(Sb + sb + 1152 + g * 8) = yo[g];
        #pragma unroll
        for (int g = 0; g < 3; ++g) *(s16x8*)(Sb + sb + 1728 + g * 8) = zo[g];
    }
    #pragma unroll
    for (int off = 32; off > 0; off >>= 1) {
        r += __shfl_down(r, off);
        d += __shfl_down(d, off);
    }
    __shared__ float sr[4], sd[4];
    int lane = threadIdx.x & 63, wid = threadIdx.x >> 6;
    if (lane == 0) { sr[wid] = r; sd[wid] = d; }
    __syncthreads();
    if (threadIdx.x == 0) {
        int bk = blockIdx.x & 31;
        atomicAdd(&redcur[bk],      sr[0] + sr[1] + sr[2] + sr[3]);
        atomicAdd(&redcur[32 + bk], sd[0] + sd[1] + sd[2] + sd[3]);
    }
}

// ---------- bf16 MFMA GEMM: C[M,N] = A[M,K] @ Wt[N,K]^T + bias ---------------
// 256 thr = 4 waves (1 M x 4 N), tile 32x128, BK templated, 16x16x32 MFMA.
// QACC: q-atomics into slot[64+bk]; LAST block also computes alpha -> slot[96]
// using dbuck slot[32:64] (done-counter at slot[97], pre-zeroed per step).
template <int BK, bool RELU, bool QACC, bool BF16OUT, int NB>
__global__ __launch_bounds__(256) void k_gemm(const ushort* __restrict__ A,
                                              const ushort* __restrict__ Wt,
                                              const float* __restrict__ bias,
                                              void* __restrict__ Cout,
                                              int K, int N,
                                              float* __restrict__ slot) {
    __shared__ ushort As[32 * BK];
    __shared__ ushort Bs[128 * BK];
    const int tid = threadIdx.x;
    const int bx = blockIdx.x;
    const int m0 = (bx / NB) * 32;
    const int n0 = (bx % NB) * 128;
    const int wave = tid >> 6, lane = tid & 63;
    const int wn = wave * 32;
    const int lm = lane & 15, quad = lane >> 4;
    constexpr int CPB = BK / 8;              // 16B chunks per row

    f32x4 acc[2][2];
    #pragma unroll
    for (int i = 0; i < 2; ++i)
        #pragma unroll
        for (int j = 0; j < 2; ++j) acc[i][j] = (f32x4){0.f, 0.f, 0.f, 0.f};

    for (int k0 = 0; k0 < K; k0 += BK) {
        #pragma unroll
        for (int c = tid; c < 32 * CPB; c += 256) {      // A: 32 rows
            int rr = c / CPB, kq = (c % CPB) * 8;
            gload_lds16(A + (size_t)(m0 + rr) * K + k0 + kq, &As[c * 8]);
        }
        #pragma unroll
        for (int c = tid; c < 128 * CPB; c += 256) {     // B: 128 rows
            int rr = c / CPB, kq = (c % CPB) * 8;
            gload_lds16(Wt + (size_t)(n0 + rr) * K + k0 + kq, &Bs[c * 8]);
        }
        __syncthreads();
        #pragma unroll
        for (int kk = 0; kk < BK; kk += 32) {
            s16x8 af[2], bfr[2];
            #pragma unroll
            for (int i = 0; i < 2; ++i)
                af[i] = *(const s16x8*)&As[(i * 16 + lm) * BK + kk + quad * 8];
            #pragma unroll
            for (int j = 0; j < 2; ++j)
                bfr[j] = *(const s16x8*)&Bs[(wn + j * 16 + lm) * BK + kk + quad * 8];
            #pragma unroll
            for (int i = 0; i < 2; ++i)
                #pragma unroll
                for (int j = 0; j < 2; ++j)
                    acc[i][j] = __builtin_amdgcn_mfma_f32_16x16x32_bf16(af[i], bfr[j], acc[i][j], 0, 0, 0);
        }
        __syncthreads();
    }

    float q = 0.f;
    #pragma unroll
    for (int j = 0; j < 2; ++j) {
        int col = n0 + wn + j * 16 + lm;
        float bb = bias[col];
        #pragma unroll
        for (int i = 0; i < 2; ++i) {
            #pragma unroll
            for (int rr = 0; rr < 4; ++rr) {
                int row = m0 + i * 16 + quad * 4 + rr;
                float c = acc[i][j][rr] + bb;
                if (RELU) c = fmaxf(c, 0.f);
                if (QACC) q += c * c;
                if (BF16OUT) ((ushort*)Cout)[(size_t)row * N + col] = f2bf(c);
                else         ((float*)Cout)[(size_t)row * N + col] = c;
            }
        }
    }
    if (QACC) {
        #pragma unroll
        for (int off = 32; off > 0; off >>= 1) q += __shfl_down(q, off);
        __shared__ float sq[4];
        __shared__ int sLast;
        if (lane == 0) sq[wave] = q;
        __syncthreads();
        if (tid == 0) {
            atomicAdd(&slot[64 + (bx & 31)], sq[0] + sq[1] + sq[2] + sq[3]);
            __threadfence();
            unsigned old = atomicAdd((unsigned int*)(slot + 97), 1u);
            sLast = (old == (unsigned)(gridDim.x - 1)) ? 1 : 0;
        }
        __syncthreads();
        if (sLast && tid < 64) {
            __threadfence();   // acquire: see all blocks' q atomics
            float v = (tid < 32) ? slot[32 + tid] : slot[64 + (tid - 32)];
            #pragma unroll
            for (int off = 16; off > 0; off >>= 1) v += __shfl_down(v, off);
            float Q = __shfl(v, 32);
            if (tid == 0) {
                float Qs = 1.5f * Q + 1e-12f;
                float b  = 0.99f * fmaxf(v, 0.f);
                slot[96] = sqrtf(fminf(b / Qs, 1.f));  // alpha for next step
            }
        }
    }
}

// ---------- finish: p_final (bf16->f32) ; block 0 folds residuals ------------
__global__ __launch_bounds__(256) void k_finish(const ushort* __restrict__ Sb,
                                                float4* __restrict__ out4,
                                                const float* __restrict__ red,
                                                float* __restrict__ res_out,
                                                int total4 /* B*144 */) {
    int i = blockIdx.x * 256 + threadIdx.x;
    if (blockIdx.x == 0 && threadIdx.x < TS) {
        const float* rb = red + (size_t)(threadIdx.x + 1) * RSL;
        float s = 0.f;
        #pragma unroll
        for (int c = 0; c < 32; ++c) s += rb[c];
        res_out[threadIdx.x] = sqrtf(s + 1e-12f);
    }
    if (i >= total4) return;
    int sample = i / 144;
    int j = i - sample * 144;
    const ushort* p = Sb + (size_t)sample * INF + 576 + j * 4;
    float4 o;
    o.x = bf2f(p[0]); o.y = bf2f(p[1]); o.z = bf2f(p[2]); o.w = bf2f(p[3]);
    out4[i] = o;
}

extern "C" void kernel_launch(void* const* d_in, const int* in_sizes, int n_in,
                              void* d_out, int out_size, void* d_ws, size_t ws_size,
                              hipStream_t stream) {
    const float* noisy = (const float*)d_in[0];
    const float* W1 = (const float*)d_in[1];
    const float* b1 = (const float*)d_in[2];
    const float* W2 = (const float*)d_in[3];
    const float* b2 = (const float*)d_in[4];
    const float* W3 = (const float*)d_in[5];
    const float* b3 = (const float*)d_in[6];
    const int B = in_sizes[0] / 64;   // 16384

    // workspace layout (~132 MB)
    ushort* Sb  = (ushort*)d_ws;                        // [B,2304] bf16
    ushort* uv  = Sb + (size_t)B * INF;                 // [B,1152] bf16
    ushort* h1  = uv + (size_t)B * OUTF;                // [B,256]  bf16
    ushort* h2  = h1 + (size_t)B * HID;                 // [B,256]  bf16
    ushort* Wt1 = h2 + (size_t)B * HID;                 // [256,2304] bf16
    ushort* Wt2 = Wt1 + (size_t)HID * INF;              // [256,256]  bf16
    ushort* Wt3 = Wt2 + (size_t)HID * HID;              // [1152,256] bf16
    float*  red = (float*)(Wt3 + (size_t)OUTF * HID);   // 21 slots x RSL

    float* p_out   = (float*)d_out;                     // [B,576]
    float* res_out = p_out + (size_t)B * SVEC;          // [20]

    const int tot8S = B * 288;   // s16x8 slots in Sb
    const int tot24 = B * 24;    // 24-elem groups per chunk
    const int tot4  = B * 144;   // float4 units of output 0

    k_init<<<(tot8S + 255) / 256, 256, 0, stream>>>(Sb, (const float4*)noisy, tot8S);
    k_zero<<<(21 * RSL + 127) / 128, 128, 0, stream>>>(red, 21 * RSL);
    k_zero<<<((B * OUTF / 2) + 127) / 128, 128, 0, stream>>>((float*)uv, B * OUTF / 2);
    k_wt<<<(HID * INF + 255) / 256, 256, 0, stream>>>(W1, Wt1, INF, HID, HID * INF);
    k_wt<<<(HID * HID + 255) / 256, 256, 0, stream>>>(W2, Wt2, HID, HID, HID * HID);
    k_wt<<<(OUTF * HID + 255) / 256, 256, 0, stream>>>(W3, Wt3, HID, OUTF, OUTF * HID);

    const int gfb = (tot24 + 255) / 256;     // 1536 blocks
    const int g1  = (B / 32) * 2;            // 1024 blocks (NB=2)
    const int g2  = (B / 32) * 2;            // 1024 blocks (NB=2)
    const int g3  = (B / 32) * 9;            // 4608 blocks (NB=9)

    for (int n = 0; n < TS; ++n) {
        float an = (float)n / ((float)n + 3.0f);
        float* redprev = red + (size_t)n * RSL;      // alpha source (slot n)
        float* redcur  = red + (size_t)(n + 1) * RSL;
        k_fbs<<<gfb, 256, 0, stream>>>(Sb, uv, redprev + 96, redcur, an, tot24);
        k_gemm<64, true,  false, true, 2><<<g1, 256, 0, stream>>>(Sb, Wt1, b1, h1, INF, HID, nullptr);
        k_gemm<64, true,  false, true, 2><<<g2, 256, 0, stream>>>(h1, Wt2, b2, h2, HID, HID, nullptr);
        k_gemm<64, false, true,  true, 9><<<g3, 256, 0, stream>>>(h2, Wt3, b3, uv, HID, OUTF, redcur);
    }
    k_finish<<<(tot4 + 255) / 256, 256, 0, stream>>>(Sb, (float4*)p_out,
                                                     red, res_out, tot4);
}

// Round 12
// 5568.230 us; speedup vs baseline: 1.0729x; 1.0729x over previous
//
#include <hip/hip_runtime.h>
#include <math.h>

constexpr int SVEC = 576;    // N_CH * 64
constexpr int INF  = 2304;   // 4 * SVEC
constexpr int HID  = 256;
constexpr int OUTF = 1152;   // 2 * SVEC
constexpr int TS   = 20;
constexpr int RSL  = 104;    // slot: r[0:32] d[32:64] q[64:96]

// ---------- helpers ----------------------------------------------------------
__device__ __forceinline__ ushort f2bf(float f) {    // RNE f32->bf16
    union { float f; unsigned u; } a; a.f = f;
    unsigned r = a.u + 0x7fff + ((a.u >> 16) & 1);
    return (ushort)(r >> 16);
}
__device__ __forceinline__ float bf2f(ushort b) {
    union { unsigned u; float f; } a; a.u = ((unsigned)b) << 16;
    return a.f;
}

__device__ __forceinline__ void gload_lds16(const void* g, void* l) {
    __builtin_amdgcn_global_load_lds(
        (const __attribute__((address_space(1))) void*)g,
        (__attribute__((address_space(3))) void*)l, 16, 0, 0);
}

typedef short  s16x8 __attribute__((ext_vector_type(8)));
typedef float  f32x4 __attribute__((ext_vector_type(4)));

// ---------- init: Sb(bf16) = [x|p|y|z] all = [noisy, 0...] -------------------
__global__ __launch_bounds__(256) void k_init(ushort* __restrict__ Sb,
                                              const float4* __restrict__ noisy4,
                                              int tot8) {
    int i = blockIdx.x * 256 + threadIdx.x;
    if (i >= tot8) return;
    int sample = i / 288;
    int j = i - sample * 288;       // slot within sample
    int jc = j % 72;                // slot within chunk
    s16x8 o = (s16x8){0,0,0,0,0,0,0,0};
    if (jc < 8) {                   // first 64 elems = noisy
        float4 a = noisy4[sample * 16 + jc * 2];
        float4 b = noisy4[sample * 16 + jc * 2 + 1];
        ushort* u = (ushort*)&o;
        u[0]=f2bf(a.x); u[1]=f2bf(a.y); u[2]=f2bf(a.z); u[3]=f2bf(a.w);
        u[4]=f2bf(b.x); u[5]=f2bf(b.y); u[6]=f2bf(b.z); u[7]=f2bf(b.w);
    }
    *(s16x8*)&Sb[(size_t)i * 8] = o;
}

__global__ __launch_bounds__(128) void k_zero(float* __restrict__ p, int n) {
    int i = blockIdx.x * 128 + threadIdx.x;
    if (i < n) p[i] = 0.f;
}

// ---------- weight transpose + bf16 convert: Wt[n*K+k] = W[k*N+n] ------------
__global__ __launch_bounds__(256) void k_wt(const float* __restrict__ W,
                                            ushort* __restrict__ Wt,
                                            int K, int N, int total) {
    int i = blockIdx.x * 256 + threadIdx.x;
    if (i >= total) return;
    int n = i / K, k = i - n * K;
    Wt[i] = f2bf(W[(size_t)k * N + n]);
}

// ---------- elementwise FBS (in-place on bf16 Sb); 24 elems per thread -------
// Fully barrier-free: inline per-wave alpha (redundant, deterministic),
// per-wave r/d atomics, 18 independent 16B loads in flight.
__global__ __launch_bounds__(256) void k_fbs(ushort* __restrict__ Sb,
                                             const ushort* __restrict__ uv,
                                             const float* __restrict__ redprev,
                                             float* __restrict__ redcur,
                                             float an, int tot24 /* B*24 */) {
    const int lane = threadIdx.x & 63, wave = threadIdx.x >> 6;
    // ---- inline alpha: slot[32+lane] covers d[0:32]|q[0:32]
    float av = redprev[32 + lane];
    #pragma unroll
    for (int off = 16; off > 0; off >>= 1) av += __shfl_down(av, off);
    float dsum = __shfl(av, 0), qsum = __shfl(av, 32);
    const float al = sqrtf(fminf(0.99f * fmaxf(dsum, 0.f) /
                                 (1.5f * qsum + 1e-12f), 1.f));

    int i = blockIdx.x * 256 + threadIdx.x;
    float r = 0.f, d = 0.f;
    if (i < tot24) {
        int sample = i / 24;
        int j24 = (i - sample * 24) * 24;        // elem offset within chunk
        size_t sb = (size_t)sample * INF + j24;
        size_t ub = (size_t)sample * OUTF + j24;
        s16x8 x8[3], p8[3], y8[3], z8[3], u8[3], v8[3];
        #pragma unroll
        for (int g = 0; g < 3; ++g) x8[g] = *(const s16x8*)(Sb + sb + g * 8);
        #pragma unroll
        for (int g = 0; g < 3; ++g) p8[g] = *(const s16x8*)(Sb + sb + 576 + g * 8);
        #pragma unroll
        for (int g = 0; g < 3; ++g) y8[g] = *(const s16x8*)(Sb + sb + 1152 + g * 8);
        #pragma unroll
        for (int g = 0; g < 3; ++g) z8[g] = *(const s16x8*)(Sb + sb + 1728 + g * 8);
        #pragma unroll
        for (int g = 0; g < 3; ++g) u8[g] = *(const s16x8*)(uv + ub + g * 8);
        #pragma unroll
        for (int g = 0; g < 3; ++g) v8[g] = *(const s16x8*)(uv + ub + 576 + g * 8);
        s16x8 xo[3], po[3], yo[3], zo[3];
        #pragma unroll
        for (int g = 0; g < 3; ++g) {
            const ushort* X = (const ushort*)&x8[g]; const ushort* P = (const ushort*)&p8[g];
            const ushort* Y = (const ushort*)&y8[g]; const ushort* Z = (const ushort*)&z8[g];
            const ushort* U = (const ushort*)&u8[g]; const ushort* V = (const ushort*)&v8[g];
            ushort* XO = (ushort*)&xo[g]; ushort* PO = (ushort*)&po[g];
            ushort* YO = (ushort*)&yo[g]; ushort* ZO = (ushort*)&zo[g];
            #pragma unroll
            for (int c = 0; c < 8; ++c) {
                float x = bf2f(X[c]), p = bf2f(P[c]);
                float yv = bf2f(Y[c]), zv = bf2f(Z[c]);
                float u = al * bf2f(U[c]), v = al * bf2f(V[c]);
                float y  = x + an * (yv - x) + u;
                float dz = an * (zv - p);
                float z  = x + an * (p - x) + dz + u + v;
                float zm = z - y;
                float t  = fabsf(zm) - 0.1f;
                float pr = (t > 0.f) ? copysignf(t, zm) : 0.f;
                float xn = x + (pr - z) + dz;
                XO[c] = f2bf(xn); PO[c] = f2bf(pr); YO[c] = f2bf(y); ZO[c] = f2bf(z);
                float e1 = pr - y; r += e1 * e1;
                float e2 = xn - z; d += e2 * e2;
            }
        }
        #pragma unroll
        for (int g = 0; g < 3; ++g) *(s16x8*)(Sb + sb + g * 8)        = xo[g];
        #pragma unroll
        for (int g = 0; g < 3; ++g) *(s16x8*)(Sb + sb + 576 + g * 8)  = po[g];
        #pragma unroll
        for (int g = 0; g < 3; ++g) *(s16x8*)(Sb + sb + 1152 + g * 8) = yo[g];
        #pragma unroll
        for (int g = 0; g < 3; ++g) *(s16x8*)(Sb + sb + 1728 + g * 8) = zo[g];
    }
    #pragma unroll
    for (int off = 32; off > 0; off >>= 1) {
        r += __shfl_down(r, off);
        d += __shfl_down(d, off);
    }
    if (lane == 0) {
        int bk = ((blockIdx.x << 2) | wave) & 31;
        atomicAdd(&redcur[bk],      r);
        atomicAdd(&redcur[32 + bk], d);
    }
}

// ---------- bf16 MFMA GEMM: C[M,N] = A[M,K] @ Wt[N,K]^T + bias ---------------
// 256 thr = 4 waves (1 M x 4 N), tile 32x128, BK templated, 16x16x32 MFMA.
template <int BK, bool RELU, bool QACC, bool BF16OUT, int NB>
__global__ __launch_bounds__(256) void k_gemm(const ushort* __restrict__ A,
                                              const ushort* __restrict__ Wt,
                                              const float* __restrict__ bias,
                                              void* __restrict__ Cout,
                                              int K, int N,
                                              float* __restrict__ qbuck) {
    __shared__ ushort As[32 * BK];
    __shared__ ushort Bs[128 * BK];
    const int tid = threadIdx.x;
    const int bx = blockIdx.x;
    const int m0 = (bx / NB) * 32;
    const int n0 = (bx % NB) * 128;
    const int wave = tid >> 6, lane = tid & 63;
    const int wn = wave * 32;
    const int lm = lane & 15, quad = lane >> 4;
    constexpr int CPB = BK / 8;              // 16B chunks per row

    f32x4 acc[2][2];
    #pragma unroll
    for (int i = 0; i < 2; ++i)
        #pragma unroll
        for (int j = 0; j < 2; ++j) acc[i][j] = (f32x4){0.f, 0.f, 0.f, 0.f};

    for (int k0 = 0; k0 < K; k0 += BK) {
        #pragma unroll
        for (int c = tid; c < 32 * CPB; c += 256) {      // A: 32 rows
            int rr = c / CPB, kq = (c % CPB) * 8;
            gload_lds16(A + (size_t)(m0 + rr) * K + k0 + kq, &As[c * 8]);
        }
        #pragma unroll
        for (int c = tid; c < 128 * CPB; c += 256) {     // B: 128 rows
            int rr = c / CPB, kq = (c % CPB) * 8;
            gload_lds16(Wt + (size_t)(n0 + rr) * K + k0 + kq, &Bs[c * 8]);
        }
        __syncthreads();
        #pragma unroll
        for (int kk = 0; kk < BK; kk += 32) {
            s16x8 af[2], bfr[2];
            #pragma unroll
            for (int i = 0; i < 2; ++i)
                af[i] = *(const s16x8*)&As[(i * 16 + lm) * BK + kk + quad * 8];
            #pragma unroll
            for (int j = 0; j < 2; ++j)
                bfr[j] = *(const s16x8*)&Bs[(wn + j * 16 + lm) * BK + kk + quad * 8];
            #pragma unroll
            for (int i = 0; i < 2; ++i)
                #pragma unroll
                for (int j = 0; j < 2; ++j)
                    acc[i][j] = __builtin_amdgcn_mfma_f32_16x16x32_bf16(af[i], bfr[j], acc[i][j], 0, 0, 0);
        }
        __syncthreads();
    }

    float q = 0.f;
    #pragma unroll
    for (int j = 0; j < 2; ++j) {
        int col = n0 + wn + j * 16 + lm;
        float bb = bias[col];
        #pragma unroll
        for (int i = 0; i < 2; ++i) {
            #pragma unroll
            for (int rr = 0; rr < 4; ++rr) {
                int row = m0 + i * 16 + quad * 4 + rr;
                float c = acc[i][j][rr] + bb;
                if (RELU) c = fmaxf(c, 0.f);
                if (QACC) q += c * c;
                if (BF16OUT) ((ushort*)Cout)[(size_t)row * N + col] = f2bf(c);
                else         ((float*)Cout)[(size_t)row * N + col] = c;
            }
        }
    }
    if (QACC) {
        #pragma unroll
        for (int off = 32; off > 0; off >>= 1) q += __shfl_down(q, off);
        if (lane == 0) atomicAdd(&qbuck[((bx << 2) | wave) & 31], q);
    }
}

// ---------- finish: p_final (bf16->f32) ; block 0 folds residuals ------------
__global__ __launch_bounds__(256) void k_finish(const ushort* __restrict__ Sb,
                                                float4* __restrict__ out4,
                                                const float* __restrict__ red,
                                                float* __restrict__ res_out,
                                                int total4 /* B*144 */) {
    int i = blockIdx.x * 256 + threadIdx.x;
    if (blockIdx.x == 0 && threadIdx.x < TS) {
        const float* rb = red + (size_t)(threadIdx.x + 1) * RSL;
        float s = 0.f;
        #pragma unroll
        for (int c = 0; c < 32; ++c) s += rb[c];
        res_out[threadIdx.x] = sqrtf(s + 1e-12f);
    }
    if (i >= total4) return;
    int sample = i / 144;
    int j = i - sample * 144;
    const ushort* p = Sb + (size_t)sample * INF + 576 + j * 4;
    float4 o;
    o.x = bf2f(p[0]); o.y = bf2f(p[1]); o.z = bf2f(p[2]); o.w = bf2f(p[3]);
    out4[i] = o;
}

extern "C" void kernel_launch(void* const* d_in, const int* in_sizes, int n_in,
                              void* d_out, int out_size, void* d_ws, size_t ws_size,
                              hipStream_t stream) {
    const float* noisy = (const float*)d_in[0];
    const float* W1 = (const float*)d_in[1];
    const float* b1 = (const float*)d_in[2];
    const float* W2 = (const float*)d_in[3];
    const float* b2 = (const float*)d_in[4];
    const float* W3 = (const float*)d_in[5];
    const float* b3 = (const float*)d_in[6];
    const int B = in_sizes[0] / 64;   // 16384

    // workspace layout (~132 MB)
    ushort* Sb  = (ushort*)d_ws;                        // [B,2304] bf16
    ushort* uv  = Sb + (size_t)B * INF;                 // [B,1152] bf16
    ushort* h1  = uv + (size_t)B * OUTF;                // [B,256]  bf16
    ushort* h2  = h1 + (size_t)B * HID;                 // [B,256]  bf16
    ushort* Wt1 = h2 + (size_t)B * HID;                 // [256,2304] bf16
    ushort* Wt2 = Wt1 + (size_t)HID * INF;              // [256,256]  bf16
    ushort* Wt3 = Wt2 + (size_t)HID * HID;              // [1152,256] bf16
    float*  red = (float*)(Wt3 + (size_t)OUTF * HID);   // 21 slots x RSL

    float* p_out   = (float*)d_out;                     // [B,576]
    float* res_out = p_out + (size_t)B * SVEC;          // [20]

    const int tot8S = B * 288;   // s16x8 slots in Sb
    const int tot24 = B * 24;    // 24-elem groups per chunk
    const int tot4  = B * 144;   // float4 units of output 0

    k_init<<<(tot8S + 255) / 256, 256, 0, stream>>>(Sb, (const float4*)noisy, tot8S);
    k_zero<<<(21 * RSL + 127) / 128, 128, 0, stream>>>(red, 21 * RSL);
    k_zero<<<((B * OUTF / 2) + 127) / 128, 128, 0, stream>>>((float*)uv, B * OUTF / 2);
    k_wt<<<(HID * INF + 255) / 256, 256, 0, stream>>>(W1, Wt1, INF, HID, HID * INF);
    k_wt<<<(HID * HID + 255) / 256, 256, 0, stream>>>(W2, Wt2, HID, HID, HID * HID);
    k_wt<<<(OUTF * HID + 255) / 256, 256, 0, stream>>>(W3, Wt3, HID, OUTF, OUTF * HID);

    const int gfb = (tot24 + 255) / 256;     // 1536 blocks
    const int g1  = (B / 32) * 2;            // 1024 blocks (NB=2)
    const int g2  = (B / 32) * 2;            // 1024 blocks (NB=2)
    const int g3  = (B / 32) * 9;            // 4608 blocks (NB=9)

    for (int n = 0; n < TS; ++n) {
        float an = (float)n / ((float)n + 3.0f);
        float* redprev = red + (size_t)n * RSL;      // alpha source (slot n)
        float* redcur  = red + (size_t)(n + 1) * RSL;
        k_fbs<<<gfb, 256, 0, stream>>>(Sb, uv, redprev, redcur, an, tot24);
        k_gemm<64, true,  false, true, 2><<<g1, 256, 0, stream>>>(Sb, Wt1, b1, h1, INF, HID, nullptr);
        k_gemm<64, true,  false, true, 2><<<g2, 256, 0, stream>>>(h1, Wt2, b2, h2, HID, HID, nullptr);
        k_gemm<32, false, true,  true, 9><<<g3, 256, 0, stream>>>(h2, Wt3, b3, uv, HID, OUTF, redcur + 64);
    }
    k_finish<<<(tot4 + 255) / 256, 256, 0, stream>>>(Sb, (float4*)p_out,
                                                     red, res_out, tot4);
}

// Round 13
// 2488.976 us; speedup vs baseline: 2.4004x; 2.2372x over previous
//
#include <hip/hip_runtime.h>
#include <math.h>

constexpr int SVEC = 576;    // N_CH * 64
constexpr int INF  = 2304;   // 4 * SVEC
constexpr int HID  = 256;
constexpr int OUTF = 1152;   // 2 * SVEC
constexpr int TS   = 20;
// red slot layout (line-spread buckets, 1 bucket = 1 cache line):
//   r[b] at b*16, d[b] at 512+b*16, q[b] at 1024+b*16, b in 0..31
constexpr int RSL  = 1536;   // floats per step slot (6 KB)

// ---------- helpers ----------------------------------------------------------
__device__ __forceinline__ ushort f2bf(float f) {    // RNE f32->bf16
    union { float f; unsigned u; } a; a.f = f;
    unsigned r = a.u + 0x7fff + ((a.u >> 16) & 1);
    return (ushort)(r >> 16);
}
__device__ __forceinline__ float bf2f(ushort b) {
    union { unsigned u; float f; } a; a.u = ((unsigned)b) << 16;
    return a.f;
}

__device__ __forceinline__ void gload_lds16(const void* g, void* l) {
    __builtin_amdgcn_global_load_lds(
        (const __attribute__((address_space(1))) void*)g,
        (__attribute__((address_space(3))) void*)l, 16, 0, 0);
}

typedef short  s16x8 __attribute__((ext_vector_type(8)));
typedef float  f32x4 __attribute__((ext_vector_type(4)));

// ---------- init: Sb(bf16) = [x|p|y|z] all = [noisy, 0...] -------------------
__global__ __launch_bounds__(256) void k_init(ushort* __restrict__ Sb,
                                              const float4* __restrict__ noisy4,
                                              int tot8) {
    int i = blockIdx.x * 256 + threadIdx.x;
    if (i >= tot8) return;
    int sample = i / 288;
    int j = i - sample * 288;       // slot within sample
    int jc = j % 72;                // slot within chunk
    s16x8 o = (s16x8){0,0,0,0,0,0,0,0};
    if (jc < 8) {                   // first 64 elems = noisy
        float4 a = noisy4[sample * 16 + jc * 2];
        float4 b = noisy4[sample * 16 + jc * 2 + 1];
        ushort* u = (ushort*)&o;
        u[0]=f2bf(a.x); u[1]=f2bf(a.y); u[2]=f2bf(a.z); u[3]=f2bf(a.w);
        u[4]=f2bf(b.x); u[5]=f2bf(b.y); u[6]=f2bf(b.z); u[7]=f2bf(b.w);
    }
    *(s16x8*)&Sb[(size_t)i * 8] = o;
}

__global__ __launch_bounds__(128) void k_zero(float* __restrict__ p, int n) {
    int i = blockIdx.x * 128 + threadIdx.x;
    if (i < n) p[i] = 0.f;
}

// ---------- weight transpose + bf16 convert: Wt[n*K+k] = W[k*N+n] ------------
__global__ __launch_bounds__(256) void k_wt(const float* __restrict__ W,
                                            ushort* __restrict__ Wt,
                                            int K, int N, int total) {
    int i = blockIdx.x * 256 + threadIdx.x;
    if (i >= total) return;
    int n = i / K, k = i - n * K;
    Wt[i] = f2bf(W[(size_t)k * N + n]);
}

// ---------- elementwise FBS (in-place on bf16 Sb); 24 elems per thread -------
// Barrier-free; inline per-wave alpha from prev slot's line-spread d/q buckets;
// per-wave r/d atomics to line-spread buckets.
__global__ __launch_bounds__(256) void k_fbs(ushort* __restrict__ Sb,
                                             const ushort* __restrict__ uv,
                                             const float* __restrict__ redprev,
                                             float* __restrict__ redcur,
                                             float an, int tot24 /* B*24 */) {
    const int lane = threadIdx.x & 63, wave = threadIdx.x >> 6;
    // ---- inline alpha: lanes 0..31 read d buckets, 32..63 read q buckets
    float av = (lane < 32) ? redprev[512 + lane * 16]
                           : redprev[1024 + (lane - 32) * 16];
    #pragma unroll
    for (int off = 16; off > 0; off >>= 1) av += __shfl_down(av, off);
    float dsum = __shfl(av, 0), qsum = __shfl(av, 32);
    const float al = sqrtf(fminf(0.99f * fmaxf(dsum, 0.f) /
                                 (1.5f * qsum + 1e-12f), 1.f));

    int i = blockIdx.x * 256 + threadIdx.x;
    float r = 0.f, d = 0.f;
    if (i < tot24) {
        int sample = i / 24;
        int j24 = (i - sample * 24) * 24;        // elem offset within chunk
        size_t sb = (size_t)sample * INF + j24;
        size_t ub = (size_t)sample * OUTF + j24;
        s16x8 x8[3], p8[3], y8[3], z8[3], u8[3], v8[3];
        #pragma unroll
        for (int g = 0; g < 3; ++g) x8[g] = *(const s16x8*)(Sb + sb + g * 8);
        #pragma unroll
        for (int g = 0; g < 3; ++g) p8[g] = *(const s16x8*)(Sb + sb + 576 + g * 8);
        #pragma unroll
        for (int g = 0; g < 3; ++g) y8[g] = *(const s16x8*)(Sb + sb + 1152 + g * 8);
        #pragma unroll
        for (int g = 0; g < 3; ++g) z8[g] = *(const s16x8*)(Sb + sb + 1728 + g * 8);
        #pragma unroll
        for (int g = 0; g < 3; ++g) u8[g] = *(const s16x8*)(uv + ub + g * 8);
        #pragma unroll
        for (int g = 0; g < 3; ++g) v8[g] = *(const s16x8*)(uv + ub + 576 + g * 8);
        s16x8 xo[3], po[3], yo[3], zo[3];
        #pragma unroll
        for (int g = 0; g < 3; ++g) {
            const ushort* X = (const ushort*)&x8[g]; const ushort* P = (const ushort*)&p8[g];
            const ushort* Y = (const ushort*)&y8[g]; const ushort* Z = (const ushort*)&z8[g];
            const ushort* U = (const ushort*)&u8[g]; const ushort* V = (const ushort*)&v8[g];
            ushort* XO = (ushort*)&xo[g]; ushort* PO = (ushort*)&po[g];
            ushort* YO = (ushort*)&yo[g]; ushort* ZO = (ushort*)&zo[g];
            #pragma unroll
            for (int c = 0; c < 8; ++c) {
                float x = bf2f(X[c]), p = bf2f(P[c]);
                float yv = bf2f(Y[c]), zv = bf2f(Z[c]);
                float u = al * bf2f(U[c]), v = al * bf2f(V[c]);
                float y  = x + an * (yv - x) + u;
                float dz = an * (zv - p);
                float z  = x + an * (p - x) + dz + u + v;
                float zm = z - y;
                float t  = fabsf(zm) - 0.1f;
                float pr = (t > 0.f) ? copysignf(t, zm) : 0.f;
                float xn = x + (pr - z) + dz;
                XO[c] = f2bf(xn); PO[c] = f2bf(pr); YO[c] = f2bf(y); ZO[c] = f2bf(z);
                float e1 = pr - y; r += e1 * e1;
                float e2 = xn - z; d += e2 * e2;
            }
        }
        #pragma unroll
        for (int g = 0; g < 3; ++g) *(s16x8*)(Sb + sb + g * 8)        = xo[g];
        #pragma unroll
        for (int g = 0; g < 3; ++g) *(s16x8*)(Sb + sb + 576 + g * 8)  = po[g];
        #pragma unroll
        for (int g = 0; g < 3; ++g) *(s16x8*)(Sb + sb + 1152 + g * 8) = yo[g];
        #pragma unroll
        for (int g = 0; g < 3; ++g) *(s16x8*)(Sb + sb + 1728 + g * 8) = zo[g];
    }
    #pragma unroll
    for (int off = 32; off > 0; off >>= 1) {
        r += __shfl_down(r, off);
        d += __shfl_down(d, off);
    }
    if (lane == 0) {
        int bk = ((blockIdx.x << 2) | wave) & 31;
        atomicAdd(&redcur[bk * 16],       r);
        atomicAdd(&redcur[512 + bk * 16], d);
    }
}

// ---------- bf16 MFMA GEMM: C[M,N] = A[M,K] @ Wt[N,K]^T + bias ---------------
// 256 thr = 4 waves (1 M x 4 N), tile 32x128, BK templated, 16x16x32 MFMA.
// QACC: block-reduced single atomic per block to line-spread q bucket.
template <int BK, bool RELU, bool QACC, bool BF16OUT, int NB>
__global__ __launch_bounds__(256) void k_gemm(const ushort* __restrict__ A,
                                              const ushort* __restrict__ Wt,
                                              const float* __restrict__ bias,
                                              void* __restrict__ Cout,
                                              int K, int N,
                                              float* __restrict__ qbuck) {
    __shared__ ushort As[32 * BK];
    __shared__ ushort Bs[128 * BK];
    const int tid = threadIdx.x;
    const int bx = blockIdx.x;
    const int m0 = (bx / NB) * 32;
    const int n0 = (bx % NB) * 128;
    const int wave = tid >> 6, lane = tid & 63;
    const int wn = wave * 32;
    const int lm = lane & 15, quad = lane >> 4;
    constexpr int CPB = BK / 8;              // 16B chunks per row

    f32x4 acc[2][2];
    #pragma unroll
    for (int i = 0; i < 2; ++i)
        #pragma unroll
        for (int j = 0; j < 2; ++j) acc[i][j] = (f32x4){0.f, 0.f, 0.f, 0.f};

    for (int k0 = 0; k0 < K; k0 += BK) {
        #pragma unroll
        for (int c = tid; c < 32 * CPB; c += 256) {      // A: 32 rows
            int rr = c / CPB, kq = (c % CPB) * 8;
            gload_lds16(A + (size_t)(m0 + rr) * K + k0 + kq, &As[c * 8]);
        }
        #pragma unroll
        for (int c = tid; c < 128 * CPB; c += 256) {     // B: 128 rows
            int rr = c / CPB, kq = (c % CPB) * 8;
            gload_lds16(Wt + (size_t)(n0 + rr) * K + k0 + kq, &Bs[c * 8]);
        }
        __syncthreads();
        #pragma unroll
        for (int kk = 0; kk < BK; kk += 32) {
            s16x8 af[2], bfr[2];
            #pragma unroll
            for (int i = 0; i < 2; ++i)
                af[i] = *(const s16x8*)&As[(i * 16 + lm) * BK + kk + quad * 8];
            #pragma unroll
            for (int j = 0; j < 2; ++j)
                bfr[j] = *(const s16x8*)&Bs[(wn + j * 16 + lm) * BK + kk + quad * 8];
            #pragma unroll
            for (int i = 0; i < 2; ++i)
                #pragma unroll
                for (int j = 0; j < 2; ++j)
                    acc[i][j] = __builtin_amdgcn_mfma_f32_16x16x32_bf16(af[i], bfr[j], acc[i][j], 0, 0, 0);
        }
        __syncthreads();
    }

    float q = 0.f;
    #pragma unroll
    for (int j = 0; j < 2; ++j) {
        int col = n0 + wn + j * 16 + lm;
        float bb = bias[col];
        #pragma unroll
        for (int i = 0; i < 2; ++i) {
            #pragma unroll
            for (int rr = 0; rr < 4; ++rr) {
                int row = m0 + i * 16 + quad * 4 + rr;
                float c = acc[i][j][rr] + bb;
                if (RELU) c = fmaxf(c, 0.f);
                if (QACC) q += c * c;
                if (BF16OUT) ((ushort*)Cout)[(size_t)row * N + col] = f2bf(c);
                else         ((float*)Cout)[(size_t)row * N + col] = c;
            }
        }
    }
    if (QACC) {
        #pragma unroll
        for (int off = 32; off > 0; off >>= 1) q += __shfl_down(q, off);
        __shared__ float sq[4];
        if (lane == 0) sq[wave] = q;
        __syncthreads();
        if (tid == 0)
            atomicAdd(&qbuck[(bx & 31) * 16], sq[0] + sq[1] + sq[2] + sq[3]);
    }
}

// ---------- finish: p_final (bf16->f32) ; block 0 folds residuals ------------
__global__ __launch_bounds__(256) void k_finish(const ushort* __restrict__ Sb,
                                                float4* __restrict__ out4,
                                                const float* __restrict__ red,
                                                float* __restrict__ res_out,
                                                int total4 /* B*144 */) {
    int i = blockIdx.x * 256 + threadIdx.x;
    if (blockIdx.x == 0 && threadIdx.x < TS) {
        const float* rb = red + (size_t)(threadIdx.x + 1) * RSL;
        float s = 0.f;
        #pragma unroll
        for (int c = 0; c < 32; ++c) s += rb[c * 16];
        res_out[threadIdx.x] = sqrtf(s + 1e-12f);
    }
    if (i >= total4) return;
    int sample = i / 144;
    int j = i - sample * 144;
    const ushort* p = Sb + (size_t)sample * INF + 576 + j * 4;
    float4 o;
    o.x = bf2f(p[0]); o.y = bf2f(p[1]); o.z = bf2f(p[2]); o.w = bf2f(p[3]);
    out4[i] = o;
}

extern "C" void kernel_launch(void* const* d_in, const int* in_sizes, int n_in,
                              void* d_out, int out_size, void* d_ws, size_t ws_size,
                              hipStream_t stream) {
    const float* noisy = (const float*)d_in[0];
    const float* W1 = (const float*)d_in[1];
    const float* b1 = (const float*)d_in[2];
    const float* W2 = (const float*)d_in[3];
    const float* b2 = (const float*)d_in[4];
    const float* W3 = (const float*)d_in[5];
    const float* b3 = (const float*)d_in[6];
    const int B = in_sizes[0] / 64;   // 16384

    // workspace layout (~132 MB)
    ushort* Sb  = (ushort*)d_ws;                        // [B,2304] bf16
    ushort* uv  = Sb + (size_t)B * INF;                 // [B,1152] bf16
    ushort* h1  = uv + (size_t)B * OUTF;                // [B,256]  bf16
    ushort* h2  = h1 + (size_t)B * HID;                 // [B,256]  bf16
    ushort* Wt1 = h2 + (size_t)B * HID;                 // [256,2304] bf16
    ushort* Wt2 = Wt1 + (size_t)HID * INF;              // [256,256]  bf16
    ushort* Wt3 = Wt2 + (size_t)HID * HID;              // [1152,256] bf16
    // 64B-align red so each 16-float bucket sits on its own cache line
    float*  red = (float*)((((uintptr_t)(Wt3 + (size_t)OUTF * HID)) + 63) & ~(uintptr_t)63);

    float* p_out   = (float*)d_out;                     // [B,576]
    float* res_out = p_out + (size_t)B * SVEC;          // [20]

    const int tot8S = B * 288;   // s16x8 slots in Sb
    const int tot24 = B * 24;    // 24-elem groups per chunk
    const int tot4  = B * 144;   // float4 units of output 0

    k_init<<<(tot8S + 255) / 256, 256, 0, stream>>>(Sb, (const float4*)noisy, tot8S);
    k_zero<<<(21 * RSL + 127) / 128, 128, 0, stream>>>(red, 21 * RSL);
    k_zero<<<((B * OUTF / 2) + 127) / 128, 128, 0, stream>>>((float*)uv, B * OUTF / 2);
    k_wt<<<(HID * INF + 255) / 256, 256, 0, stream>>>(W1, Wt1, INF, HID, HID * INF);
    k_wt<<<(HID * HID + 255) / 256, 256, 0, stream>>>(W2, Wt2, HID, HID, HID * HID);
    k_wt<<<(OUTF * HID + 255) / 256, 256, 0, stream>>>(W3, Wt3, HID, OUTF, OUTF * HID);

    const int gfb = (tot24 + 255) / 256;     // 1536 blocks
    const int g1  = (B / 32) * 2;            // 1024 blocks (NB=2)
    const int g2  = (B / 32) * 2;            // 1024 blocks (NB=2)
    const int g3  = (B / 32) * 9;            // 4608 blocks (NB=9)

    for (int n = 0; n < TS; ++n) {
        float an = (float)n / ((float)n + 3.0f);
        float* redprev = red + (size_t)n * RSL;      // alpha source (slot n)
        float* redcur  = red + (size_t)(n + 1) * RSL;
        k_fbs<<<gfb, 256, 0, stream>>>(Sb, uv, redprev, redcur, an, tot24);
        k_gemm<64, true,  false, true, 2><<<g1, 256, 0, stream>>>(Sb, Wt1, b1, h1, INF, HID, nullptr);
        k_gemm<64, true,  false, true, 2><<<g2, 256, 0, stream>>>(h1, Wt2, b2, h2, HID, HID, nullptr);
        k_gemm<32, false, true,  true, 9><<<g3, 256, 0, stream>>>(h2, Wt3, b3, uv, HID, OUTF, redcur + 1024);
    }
    k_finish<<<(tot4 + 255) / 256, 256, 0, stream>>>(Sb, (float4*)p_out,
                                                     red, res_out, tot4);
}

// Round 14
// 2425.026 us; speedup vs baseline: 2.4637x; 1.0264x over previous
//
#include <hip/hip_runtime.h>
#include <math.h>

constexpr int SVEC = 576;    // N_CH * 64
constexpr int INF  = 2304;   // 4 * SVEC
constexpr int HID  = 256;
constexpr int OUTF = 1152;   // 2 * SVEC
constexpr int TS   = 20;
// red slot layout (line-spread buckets, 1 bucket = 1 cache line):
//   r[b] at b*16, d[b] at 512+b*16, q[b] at 1024+b*16, b in 0..31
constexpr int RSL  = 1536;   // floats per step slot (6 KB)

// ---------- helpers ----------------------------------------------------------
__device__ __forceinline__ ushort f2bf(float f) {    // RNE f32->bf16
    union { float f; unsigned u; } a; a.f = f;
    unsigned r = a.u + 0x7fff + ((a.u >> 16) & 1);
    return (ushort)(r >> 16);
}
__device__ __forceinline__ float bf2f(ushort b) {
    union { unsigned u; float f; } a; a.u = ((unsigned)b) << 16;
    return a.f;
}

__device__ __forceinline__ void gload_lds16(const void* g, void* l) {
    __builtin_amdgcn_global_load_lds(
        (const __attribute__((address_space(1))) void*)g,
        (__attribute__((address_space(3))) void*)l, 16, 0, 0);
}

typedef short  s16x8 __attribute__((ext_vector_type(8)));
typedef float  f32x4 __attribute__((ext_vector_type(4)));

// ---------- init: Sb(bf16) = [x|p|y|z] all = [noisy, 0...] -------------------
__global__ __launch_bounds__(256) void k_init(ushort* __restrict__ Sb,
                                              const float4* __restrict__ noisy4,
                                              int tot8) {
    int i = blockIdx.x * 256 + threadIdx.x;
    if (i >= tot8) return;
    int sample = i / 288;
    int j = i - sample * 288;       // slot within sample
    int jc = j % 72;                // slot within chunk
    s16x8 o = (s16x8){0,0,0,0,0,0,0,0};
    if (jc < 8) {                   // first 64 elems = noisy
        float4 a = noisy4[sample * 16 + jc * 2];
        float4 b = noisy4[sample * 16 + jc * 2 + 1];
        ushort* u = (ushort*)&o;
        u[0]=f2bf(a.x); u[1]=f2bf(a.y); u[2]=f2bf(a.z); u[3]=f2bf(a.w);
        u[4]=f2bf(b.x); u[5]=f2bf(b.y); u[6]=f2bf(b.z); u[7]=f2bf(b.w);
    }
    *(s16x8*)&Sb[(size_t)i * 8] = o;
}

__global__ __launch_bounds__(128) void k_zero(float* __restrict__ p, int n) {
    int i = blockIdx.x * 128 + threadIdx.x;
    if (i < n) p[i] = 0.f;
}

// ---------- weight transpose + bf16 convert: Wt[n*K+k] = W[k*N+n] ------------
__global__ __launch_bounds__(256) void k_wt(const float* __restrict__ W,
                                            ushort* __restrict__ Wt,
                                            int K, int N, int total) {
    int i = blockIdx.x * 256 + threadIdx.x;
    if (i >= total) return;
    int n = i / K, k = i - n * K;
    Wt[i] = f2bf(W[(size_t)k * N + n]);
}

// ---------- elementwise FBS (in-place on bf16 Sb); 24 elems per thread -------
// Barrier-free; inline per-wave alpha from prev slot's line-spread d/q buckets;
// per-wave r/d atomics to line-spread buckets.
__global__ __launch_bounds__(256) void k_fbs(ushort* __restrict__ Sb,
                                             const ushort* __restrict__ uv,
                                             const float* __restrict__ redprev,
                                             float* __restrict__ redcur,
                                             float an, int tot24 /* B*24 */) {
    const int lane = threadIdx.x & 63, wave = threadIdx.x >> 6;
    // ---- inline alpha: lanes 0..31 read d buckets, 32..63 read q buckets
    float av = (lane < 32) ? redprev[512 + lane * 16]
                           : redprev[1024 + (lane - 32) * 16];
    #pragma unroll
    for (int off = 16; off > 0; off >>= 1) av += __shfl_down(av, off);
    float dsum = __shfl(av, 0), qsum = __shfl(av, 32);
    const float al = sqrtf(fminf(0.99f * fmaxf(dsum, 0.f) /
                                 (1.5f * qsum + 1e-12f), 1.f));

    int i = blockIdx.x * 256 + threadIdx.x;
    float r = 0.f, d = 0.f;
    if (i < tot24) {
        int sample = i / 24;
        int j24 = (i - sample * 24) * 24;        // elem offset within chunk
        size_t sb = (size_t)sample * INF + j24;
        size_t ub = (size_t)sample * OUTF + j24;
        s16x8 x8[3], p8[3], y8[3], z8[3], u8[3], v8[3];
        #pragma unroll
        for (int g = 0; g < 3; ++g) x8[g] = *(const s16x8*)(Sb + sb + g * 8);
        #pragma unroll
        for (int g = 0; g < 3; ++g) p8[g] = *(const s16x8*)(Sb + sb + 576 + g * 8);
        #pragma unroll
        for (int g = 0; g < 3; ++g) y8[g] = *(const s16x8*)(Sb + sb + 1152 + g * 8);
        #pragma unroll
        for (int g = 0; g < 3; ++g) z8[g] = *(const s16x8*)(Sb + sb + 1728 + g * 8);
        #pragma unroll
        for (int g = 0; g < 3; ++g) u8[g] = *(const s16x8*)(uv + ub + g * 8);
        #pragma unroll
        for (int g = 0; g < 3; ++g) v8[g] = *(const s16x8*)(uv + ub + 576 + g * 8);
        s16x8 xo[3], po[3], yo[3], zo[3];
        #pragma unroll
        for (int g = 0; g < 3; ++g) {
            const ushort* X = (const ushort*)&x8[g]; const ushort* P = (const ushort*)&p8[g];
            const ushort* Y = (const ushort*)&y8[g]; const ushort* Z = (const ushort*)&z8[g];
            const ushort* U = (const ushort*)&u8[g]; const ushort* V = (const ushort*)&v8[g];
            ushort* XO = (ushort*)&xo[g]; ushort* PO = (ushort*)&po[g];
            ushort* YO = (ushort*)&yo[g]; ushort* ZO = (ushort*)&zo[g];
            #pragma unroll
            for (int c = 0; c < 8; ++c) {
                float x = bf2f(X[c]), p = bf2f(P[c]);
                float yv = bf2f(Y[c]), zv = bf2f(Z[c]);
                float u = al * bf2f(U[c]), v = al * bf2f(V[c]);
                float y  = x + an * (yv - x) + u;
                float dz = an * (zv - p);
                float z  = x + an * (p - x) + dz + u + v;
                float zm = z - y;
                float t  = fabsf(zm) - 0.1f;
                float pr = (t > 0.f) ? copysignf(t, zm) : 0.f;
                float xn = x + (pr - z) + dz;
                XO[c] = f2bf(xn); PO[c] = f2bf(pr); YO[c] = f2bf(y); ZO[c] = f2bf(z);
                float e1 = pr - y; r += e1 * e1;
                float e2 = xn - z; d += e2 * e2;
            }
        }
        #pragma unroll
        for (int g = 0; g < 3; ++g) *(s16x8*)(Sb + sb + g * 8)        = xo[g];
        #pragma unroll
        for (int g = 0; g < 3; ++g) *(s16x8*)(Sb + sb + 576 + g * 8)  = po[g];
        #pragma unroll
        for (int g = 0; g < 3; ++g) *(s16x8*)(Sb + sb + 1152 + g * 8) = yo[g];
        #pragma unroll
        for (int g = 0; g < 3; ++g) *(s16x8*)(Sb + sb + 1728 + g * 8) = zo[g];
    }
    #pragma unroll
    for (int off = 32; off > 0; off >>= 1) {
        r += __shfl_down(r, off);
        d += __shfl_down(d, off);
    }
    if (lane == 0) {
        int bk = ((blockIdx.x << 2) | wave) & 31;
        atomicAdd(&redcur[bk * 16],       r);
        atomicAdd(&redcur[512 + bk * 16], d);
    }
}

// ---------- bf16 MFMA GEMM: C[M,N] = A[M,K] @ Wt[N,K]^T + bias ---------------
// 256 thr = 4 waves (1 M x 4 N), tile 32x128, BK templated, 16x16x32 MFMA.
// LDS XOR swizzle: slot row*CPB+cs stores global chunk cs^(row&(CPB-1));
// frag read uses chunk^(row&(CPB-1)) -> row accesses spread across banks.
template <int BK, bool RELU, bool QACC, bool BF16OUT, int NB>
__global__ __launch_bounds__(256) void k_gemm(const ushort* __restrict__ A,
                                              const ushort* __restrict__ Wt,
                                              const float* __restrict__ bias,
                                              void* __restrict__ Cout,
                                              int K, int N,
                                              float* __restrict__ qbuck) {
    __shared__ ushort As[32 * BK];
    __shared__ ushort Bs[128 * BK];
    const int tid = threadIdx.x;
    const int bx = blockIdx.x;
    const int m0 = (bx / NB) * 32;
    const int n0 = (bx % NB) * 128;
    const int wave = tid >> 6, lane = tid & 63;
    const int wn = wave * 32;
    const int lm = lane & 15, quad = lane >> 4;
    constexpr int CPB = BK / 8;              // 16B chunks per row
    constexpr int SWZ = CPB - 1;

    f32x4 acc[2][2];
    #pragma unroll
    for (int i = 0; i < 2; ++i)
        #pragma unroll
        for (int j = 0; j < 2; ++j) acc[i][j] = (f32x4){0.f, 0.f, 0.f, 0.f};

    for (int k0 = 0; k0 < K; k0 += BK) {
        #pragma unroll
        for (int c = tid; c < 32 * CPB; c += 256) {      // A: 32 rows
            int row = c / CPB, cs = c % CPB;
            int src = cs ^ (row & SWZ);
            gload_lds16(A + (size_t)(m0 + row) * K + k0 + src * 8, &As[c * 8]);
        }
        #pragma unroll
        for (int c = tid; c < 128 * CPB; c += 256) {     // B: 128 rows
            int row = c / CPB, cs = c % CPB;
            int src = cs ^ (row & SWZ);
            gload_lds16(Wt + (size_t)(n0 + row) * K + k0 + src * 8, &Bs[c * 8]);
        }
        __syncthreads();
        #pragma unroll
        for (int kk = 0; kk < BK; kk += 32) {
            s16x8 af[2], bfr[2];
            #pragma unroll
            for (int i = 0; i < 2; ++i) {
                int row = i * 16 + lm;
                int ch = ((kk >> 3) + quad) ^ (row & SWZ);
                af[i] = *(const s16x8*)&As[(row * CPB + ch) * 8];
            }
            #pragma unroll
            for (int j = 0; j < 2; ++j) {
                int row = wn + j * 16 + lm;
                int ch = ((kk >> 3) + quad) ^ (row & SWZ);
                bfr[j] = *(const s16x8*)&Bs[(row * CPB + ch) * 8];
            }
            #pragma unroll
            for (int i = 0; i < 2; ++i)
                #pragma unroll
                for (int j = 0; j < 2; ++j)
                    acc[i][j] = __builtin_amdgcn_mfma_f32_16x16x32_bf16(af[i], bfr[j], acc[i][j], 0, 0, 0);
        }
        __syncthreads();
    }

    float q = 0.f;
    #pragma unroll
    for (int j = 0; j < 2; ++j) {
        int col = n0 + wn + j * 16 + lm;
        float bb = bias[col];
        #pragma unroll
        for (int i = 0; i < 2; ++i) {
            #pragma unroll
            for (int rr = 0; rr < 4; ++rr) {
                int row = m0 + i * 16 + quad * 4 + rr;
                float c = acc[i][j][rr] + bb;
                if (RELU) c = fmaxf(c, 0.f);
                if (QACC) q += c * c;
                if (BF16OUT) ((ushort*)Cout)[(size_t)row * N + col] = f2bf(c);
                else         ((float*)Cout)[(size_t)row * N + col] = c;
            }
        }
    }
    if (QACC) {
        #pragma unroll
        for (int off = 32; off > 0; off >>= 1) q += __shfl_down(q, off);
        __shared__ float sq[4];
        if (lane == 0) sq[wave] = q;
        __syncthreads();
        if (tid == 0)
            atomicAdd(&qbuck[(bx & 31) * 16], sq[0] + sq[1] + sq[2] + sq[3]);
    }
}

// ---------- finish: p_final (bf16->f32) ; block 0 folds residuals ------------
__global__ __launch_bounds__(256) void k_finish(const ushort* __restrict__ Sb,
                                                float4* __restrict__ out4,
                                                const float* __restrict__ red,
                                                float* __restrict__ res_out,
                                                int total4 /* B*144 */) {
    int i = blockIdx.x * 256 + threadIdx.x;
    if (blockIdx.x == 0 && threadIdx.x < TS) {
        const float* rb = red + (size_t)(threadIdx.x + 1) * RSL;
        float s = 0.f;
        #pragma unroll
        for (int c = 0; c < 32; ++c) s += rb[c * 16];
        res_out[threadIdx.x] = sqrtf(s + 1e-12f);
    }
    if (i >= total4) return;
    int sample = i / 144;
    int j = i - sample * 144;
    const ushort* p = Sb + (size_t)sample * INF + 576 + j * 4;
    float4 o;
    o.x = bf2f(p[0]); o.y = bf2f(p[1]); o.z = bf2f(p[2]); o.w = bf2f(p[3]);
    out4[i] = o;
}

extern "C" void kernel_launch(void* const* d_in, const int* in_sizes, int n_in,
                              void* d_out, int out_size, void* d_ws, size_t ws_size,
                              hipStream_t stream) {
    const float* noisy = (const float*)d_in[0];
    const float* W1 = (const float*)d_in[1];
    const float* b1 = (const float*)d_in[2];
    const float* W2 = (const float*)d_in[3];
    const float* b2 = (const float*)d_in[4];
    const float* W3 = (const float*)d_in[5];
    const float* b3 = (const float*)d_in[6];
    const int B = in_sizes[0] / 64;   // 16384

    // workspace layout (~132 MB)
    ushort* Sb  = (ushort*)d_ws;                        // [B,2304] bf16
    ushort* uv  = Sb + (size_t)B * INF;                 // [B,1152] bf16
    ushort* h1  = uv + (size_t)B * OUTF;                // [B,256]  bf16
    ushort* h2  = h1 + (size_t)B * HID;                 // [B,256]  bf16
    ushort* Wt1 = h2 + (size_t)B * HID;                 // [256,2304] bf16
    ushort* Wt2 = Wt1 + (size_t)HID * INF;              // [256,256]  bf16
    ushort* Wt3 = Wt2 + (size_t)HID * HID;              // [1152,256] bf16
    // 64B-align red so each 16-float bucket sits on its own cache line
    float*  red = (float*)((((uintptr_t)(Wt3 + (size_t)OUTF * HID)) + 63) & ~(uintptr_t)63);

    float* p_out   = (float*)d_out;                     // [B,576]
    float* res_out = p_out + (size_t)B * SVEC;          // [20]

    const int tot8S = B * 288;   // s16x8 slots in Sb
    const int tot24 = B * 24;    // 24-elem groups per chunk
    const int tot4  = B * 144;   // float4 units of output 0

    k_init<<<(tot8S + 255) / 256, 256, 0, stream>>>(Sb, (const float4*)noisy, tot8S);
    k_zero<<<(21 * RSL + 127) / 128, 128, 0, stream>>>(red, 21 * RSL);
    k_zero<<<((B * OUTF / 2) + 127) / 128, 128, 0, stream>>>((float*)uv, B * OUTF / 2);
    k_wt<<<(HID * INF + 255) / 256, 256, 0, stream>>>(W1, Wt1, INF, HID, HID * INF);
    k_wt<<<(HID * HID + 255) / 256, 256, 0, stream>>>(W2, Wt2, HID, HID, HID * HID);
    k_wt<<<(OUTF * HID + 255) / 256, 256, 0, stream>>>(W3, Wt3, HID, OUTF, OUTF * HID);

    const int gfb = (tot24 + 255) / 256;     // 1536 blocks
    const int g1  = (B / 32) * 2;            // 1024 blocks (NB=2)
    const int g2  = (B / 32) * 2;            // 1024 blocks (NB=2)
    const int g3  = (B / 32) * 9;            // 4608 blocks (NB=9)

    for (int n = 0; n < TS; ++n) {
        float an = (float)n / ((float)n + 3.0f);
        float* redprev = red + (size_t)n * RSL;      // alpha source (slot n)
        float* redcur  = red + (size_t)(n + 1) * RSL;
        k_fbs<<<gfb, 256, 0, stream>>>(Sb, uv, redprev, redcur, an, tot24);
        k_gemm<64, true,  false, true, 2><<<g1, 256, 0, stream>>>(Sb, Wt1, b1, h1, INF, HID, nullptr);
        k_gemm<64, true,  false, true, 2><<<g2, 256, 0, stream>>>(h1, Wt2, b2, h2, HID, HID, nullptr);
        k_gemm<32, false, true,  true, 9><<<g3, 256, 0, stream>>>(h2, Wt3, b3, uv, HID, OUTF, redcur + 1024);
    }
    k_finish<<<(tot4 + 255) / 256, 256, 0, stream>>>(Sb, (float4*)p_out,
                                                     red, res_out, tot4);
}

// Round 15
// 2267.638 us; speedup vs baseline: 2.6346x; 1.0694x over previous
//
#include <hip/hip_runtime.h>
#include <math.h>

constexpr int SVEC = 576;    // N_CH * 64
constexpr int INF  = 2304;   // 4 * SVEC
constexpr int HID  = 256;
constexpr int OUTF = 1152;   // 2 * SVEC
constexpr int TS   = 20;
// red slot layout (line-spread buckets, 1 bucket = 1 cache line):
//   r[b] at b*16, d[b] at 512+b*16, q[b] at 1024+b*16, b in 0..31
constexpr int RSL  = 1536;   // floats per step slot (6 KB)

// ---------- helpers ----------------------------------------------------------
__device__ __forceinline__ ushort f2bf(float f) {    // RNE f32->bf16
    union { float f; unsigned u; } a; a.f = f;
    unsigned r = a.u + 0x7fff + ((a.u >> 16) & 1);
    return (ushort)(r >> 16);
}
__device__ __forceinline__ float bf2f(ushort b) {
    union { unsigned u; float f; } a; a.u = ((unsigned)b) << 16;
    return a.f;
}

__device__ __forceinline__ void gload_lds16(const void* g, void* l) {
    __builtin_amdgcn_global_load_lds(
        (const __attribute__((address_space(1))) void*)g,
        (__attribute__((address_space(3))) void*)l, 16, 0, 0);
}

typedef short  s16x8 __attribute__((ext_vector_type(8)));
typedef float  f32x4 __attribute__((ext_vector_type(4)));

// ---------- init: Sb(bf16) = [x|p|y|z] all = [noisy, 0...] -------------------
__global__ __launch_bounds__(256) void k_init(ushort* __restrict__ Sb,
                                              const float4* __restrict__ noisy4,
                                              int tot8) {
    int i = blockIdx.x * 256 + threadIdx.x;
    if (i >= tot8) return;
    int sample = i / 288;
    int j = i - sample * 288;       // slot within sample
    int jc = j % 72;                // slot within chunk
    s16x8 o = (s16x8){0,0,0,0,0,0,0,0};
    if (jc < 8) {                   // first 64 elems = noisy
        float4 a = noisy4[sample * 16 + jc * 2];
        float4 b = noisy4[sample * 16 + jc * 2 + 1];
        ushort* u = (ushort*)&o;
        u[0]=f2bf(a.x); u[1]=f2bf(a.y); u[2]=f2bf(a.z); u[3]=f2bf(a.w);
        u[4]=f2bf(b.x); u[5]=f2bf(b.y); u[6]=f2bf(b.z); u[7]=f2bf(b.w);
    }
    *(s16x8*)&Sb[(size_t)i * 8] = o;
}

__global__ __launch_bounds__(128) void k_zero(float* __restrict__ p, int n) {
    int i = blockIdx.x * 128 + threadIdx.x;
    if (i < n) p[i] = 0.f;
}

// ---------- weight transpose + bf16 convert: Wt[n*K+k] = W[k*N+n] ------------
__global__ __launch_bounds__(256) void k_wt(const float* __restrict__ W,
                                            ushort* __restrict__ Wt,
                                            int K, int N, int total) {
    int i = blockIdx.x * 256 + threadIdx.x;
    if (i >= total) return;
    int n = i / K, k = i - n * K;
    Wt[i] = f2bf(W[(size_t)k * N + n]);
}

// ---------- elementwise FBS (in-place on bf16 Sb); 24 elems per thread -------
// Barrier-free; inline per-wave alpha from prev slot's line-spread d/q buckets;
// per-wave r/d atomics to line-spread buckets.
__global__ __launch_bounds__(256) void k_fbs(ushort* __restrict__ Sb,
                                             const ushort* __restrict__ uv,
                                             const float* __restrict__ redprev,
                                             float* __restrict__ redcur,
                                             float an, int tot24 /* B*24 */) {
    const int lane = threadIdx.x & 63, wave = threadIdx.x >> 6;
    // ---- inline alpha: lanes 0..31 read d buckets, 32..63 read q buckets
    float av = (lane < 32) ? redprev[512 + lane * 16]
                           : redprev[1024 + (lane - 32) * 16];
    #pragma unroll
    for (int off = 16; off > 0; off >>= 1) av += __shfl_down(av, off);
    float dsum = __shfl(av, 0), qsum = __shfl(av, 32);
    const float al = sqrtf(fminf(0.99f * fmaxf(dsum, 0.f) /
                                 (1.5f * qsum + 1e-12f), 1.f));

    int i = blockIdx.x * 256 + threadIdx.x;
    float r = 0.f, d = 0.f;
    if (i < tot24) {
        int sample = i / 24;
        int j24 = (i - sample * 24) * 24;        // elem offset within chunk
        size_t sb = (size_t)sample * INF + j24;
        size_t ub = (size_t)sample * OUTF + j24;
        s16x8 x8[3], p8[3], y8[3], z8[3], u8[3], v8[3];
        #pragma unroll
        for (int g = 0; g < 3; ++g) x8[g] = *(const s16x8*)(Sb + sb + g * 8);
        #pragma unroll
        for (int g = 0; g < 3; ++g) p8[g] = *(const s16x8*)(Sb + sb + 576 + g * 8);
        #pragma unroll
        for (int g = 0; g < 3; ++g) y8[g] = *(const s16x8*)(Sb + sb + 1152 + g * 8);
        #pragma unroll
        for (int g = 0; g < 3; ++g) z8[g] = *(const s16x8*)(Sb + sb + 1728 + g * 8);
        #pragma unroll
        for (int g = 0; g < 3; ++g) u8[g] = *(const s16x8*)(uv + ub + g * 8);
        #pragma unroll
        for (int g = 0; g < 3; ++g) v8[g] = *(const s16x8*)(uv + ub + 576 + g * 8);
        s16x8 xo[3], po[3], yo[3], zo[3];
        #pragma unroll
        for (int g = 0; g < 3; ++g) {
            const ushort* X = (const ushort*)&x8[g]; const ushort* P = (const ushort*)&p8[g];
            const ushort* Y = (const ushort*)&y8[g]; const ushort* Z = (const ushort*)&z8[g];
            const ushort* U = (const ushort*)&u8[g]; const ushort* V = (const ushort*)&v8[g];
            ushort* XO = (ushort*)&xo[g]; ushort* PO = (ushort*)&po[g];
            ushort* YO = (ushort*)&yo[g]; ushort* ZO = (ushort*)&zo[g];
            #pragma unroll
            for (int c = 0; c < 8; ++c) {
                float x = bf2f(X[c]), p = bf2f(P[c]);
                float yv = bf2f(Y[c]), zv = bf2f(Z[c]);
                float u = al * bf2f(U[c]), v = al * bf2f(V[c]);
                float y  = x + an * (yv - x) + u;
                float dz = an * (zv - p);
                float z  = x + an * (p - x) + dz + u + v;
                float zm = z - y;
                float t  = fabsf(zm) - 0.1f;
                float pr = (t > 0.f) ? copysignf(t, zm) : 0.f;
                float xn = x + (pr - z) + dz;
                XO[c] = f2bf(xn); PO[c] = f2bf(pr); YO[c] = f2bf(y); ZO[c] = f2bf(z);
                float e1 = pr - y; r += e1 * e1;
                float e2 = xn - z; d += e2 * e2;
            }
        }
        #pragma unroll
        for (int g = 0; g < 3; ++g) *(s16x8*)(Sb + sb + g * 8)        = xo[g];
        #pragma unroll
        for (int g = 0; g < 3; ++g) *(s16x8*)(Sb + sb + 576 + g * 8)  = po[g];
        #pragma unroll
        for (int g = 0; g < 3; ++g) *(s16x8*)(Sb + sb + 1152 + g * 8) = yo[g];
        #pragma unroll
        for (int g = 0; g < 3; ++g) *(s16x8*)(Sb + sb + 1728 + g * 8) = zo[g];
    }
    #pragma unroll
    for (int off = 32; off > 0; off >>= 1) {
        r += __shfl_down(r, off);
        d += __shfl_down(d, off);
    }
    if (lane == 0) {
        int bk = ((blockIdx.x << 2) | wave) & 31;
        atomicAdd(&redcur[bk * 16],       r);
        atomicAdd(&redcur[512 + bk * 16], d);
    }
}

// ---------- bf16 MFMA GEMM: C[M,N] = A[M,K] @ Wt[N,K]^T + bias ---------------
// 256 thr = 4 waves (1 M x 4 N), tile 32x128, BK templated, 16x16x32 MFMA.
// LDS XOR swizzle: slot row*CPB+cs stores global chunk cs^(row&(CPB-1));
// frag read uses chunk^(row&(CPB-1)) -> row accesses spread across banks.
template <int BK, bool RELU, bool QACC, bool BF16OUT, int NB>
__global__ __launch_bounds__(256) void k_gemm(const ushort* __restrict__ A,
                                              const ushort* __restrict__ Wt,
                                              const float* __restrict__ bias,
                                              void* __restrict__ Cout,
                                              int K, int N,
                                              float* __restrict__ qbuck) {
    __shared__ ushort As[32 * BK];
    __shared__ ushort Bs[128 * BK];
    const int tid = threadIdx.x;
    const int bx = blockIdx.x;
    const int m0 = (bx / NB) * 32;
    const int n0 = (bx % NB) * 128;
    const int wave = tid >> 6, lane = tid & 63;
    const int wn = wave * 32;
    const int lm = lane & 15, quad = lane >> 4;
    constexpr int CPB = BK / 8;              // 16B chunks per row
    constexpr int SWZ = CPB - 1;

    f32x4 acc[2][2];
    #pragma unroll
    for (int i = 0; i < 2; ++i)
        #pragma unroll
        for (int j = 0; j < 2; ++j) acc[i][j] = (f32x4){0.f, 0.f, 0.f, 0.f};

    for (int k0 = 0; k0 < K; k0 += BK) {
        #pragma unroll
        for (int c = tid; c < 32 * CPB; c += 256) {      // A: 32 rows
            int row = c / CPB, cs = c % CPB;
            int src = cs ^ (row & SWZ);
            gload_lds16(A + (size_t)(m0 + row) * K + k0 + src * 8, &As[c * 8]);
        }
        #pragma unroll
        for (int c = tid; c < 128 * CPB; c += 256) {     // B: 128 rows
            int row = c / CPB, cs = c % CPB;
            int src = cs ^ (row & SWZ);
            gload_lds16(Wt + (size_t)(n0 + row) * K + k0 + src * 8, &Bs[c * 8]);
        }
        __syncthreads();
        #pragma unroll
        for (int kk = 0; kk < BK; kk += 32) {
            s16x8 af[2], bfr[2];
            #pragma unroll
            for (int i = 0; i < 2; ++i) {
                int row = i * 16 + lm;
                int ch = ((kk >> 3) + quad) ^ (row & SWZ);
                af[i] = *(const s16x8*)&As[(row * CPB + ch) * 8];
            }
            #pragma unroll
            for (int j = 0; j < 2; ++j) {
                int row = wn + j * 16 + lm;
                int ch = ((kk >> 3) + quad) ^ (row & SWZ);
                bfr[j] = *(const s16x8*)&Bs[(row * CPB + ch) * 8];
            }
            #pragma unroll
            for (int i = 0; i < 2; ++i)
                #pragma unroll
                for (int j = 0; j < 2; ++j)
                    acc[i][j] = __builtin_amdgcn_mfma_f32_16x16x32_bf16(af[i], bfr[j], acc[i][j], 0, 0, 0);
        }
        __syncthreads();
    }

    float q = 0.f;
    #pragma unroll
    for (int j = 0; j < 2; ++j) {
        int col = n0 + wn + j * 16 + lm;
        float bb = bias[col];
        #pragma unroll
        for (int i = 0; i < 2; ++i) {
            #pragma unroll
            for (int rr = 0; rr < 4; ++rr) {
                int row = m0 + i * 16 + quad * 4 + rr;
                float c = acc[i][j][rr] + bb;
                if (RELU) c = fmaxf(c, 0.f);
                if (QACC) q += c * c;
                if (BF16OUT) ((ushort*)Cout)[(size_t)row * N + col] = f2bf(c);
                else         ((float*)Cout)[(size_t)row * N + col] = c;
            }
        }
    }
    if (QACC) {
        #pragma unroll
        for (int off = 32; off > 0; off >>= 1) q += __shfl_down(q, off);
        __shared__ float sq[4];
        if (lane == 0) sq[wave] = q;
        __syncthreads();
        if (tid == 0)
            atomicAdd(&qbuck[(bx & 31) * 16], sq[0] + sq[1] + sq[2] + sq[3]);
    }
}

// ---------- finish: p_final (bf16->f32) ; block 0 folds residuals ------------
__global__ __launch_bounds__(256) void k_finish(const ushort* __restrict__ Sb,
                                                float4* __restrict__ out4,
                                                const float* __restrict__ red,
                                                float* __restrict__ res_out,
                                                int total4 /* B*144 */) {
    int i = blockIdx.x * 256 + threadIdx.x;
    if (blockIdx.x == 0 && threadIdx.x < TS) {
        const float* rb = red + (size_t)(threadIdx.x + 1) * RSL;
        float s = 0.f;
        #pragma unroll
        for (int c = 0; c < 32; ++c) s += rb[c * 16];
        res_out[threadIdx.x] = sqrtf(s + 1e-12f);
    }
    if (i >= total4) return;
    int sample = i / 144;
    int j = i - sample * 144;
    const ushort* p = Sb + (size_t)sample * INF + 576 + j * 4;
    float4 o;
    o.x = bf2f(p[0]); o.y = bf2f(p[1]); o.z = bf2f(p[2]); o.w = bf2f(p[3]);
    out4[i] = o;
}

extern "C" void kernel_launch(void* const* d_in, const int* in_sizes, int n_in,
                              void* d_out, int out_size, void* d_ws, size_t ws_size,
                              hipStream_t stream) {
    const float* noisy = (const float*)d_in[0];
    const float* W1 = (const float*)d_in[1];
    const float* b1 = (const float*)d_in[2];
    const float* W2 = (const float*)d_in[3];
    const float* b2 = (const float*)d_in[4];
    const float* W3 = (const float*)d_in[5];
    const float* b3 = (const float*)d_in[6];
    const int B = in_sizes[0] / 64;   // 16384

    // workspace layout (~132 MB)
    ushort* Sb  = (ushort*)d_ws;                        // [B,2304] bf16
    ushort* uv  = Sb + (size_t)B * INF;                 // [B,1152] bf16
    ushort* h1  = uv + (size_t)B * OUTF;                // [B,256]  bf16
    ushort* h2  = h1 + (size_t)B * HID;                 // [B,256]  bf16
    ushort* Wt1 = h2 + (size_t)B * HID;                 // [256,2304] bf16
    ushort* Wt2 = Wt1 + (size_t)HID * INF;              // [256,256]  bf16
    ushort* Wt3 = Wt2 + (size_t)HID * HID;              // [1152,256] bf16
    // 64B-align red so each 16-float bucket sits on its own cache line
    float*  red = (float*)((((uintptr_t)(Wt3 + (size_t)OUTF * HID)) + 63) & ~(uintptr_t)63);

    float* p_out   = (float*)d_out;                     // [B,576]
    float* res_out = p_out + (size_t)B * SVEC;          // [20]

    const int tot8S = B * 288;   // s16x8 slots in Sb
    const int tot24 = B * 24;    // 24-elem groups per chunk
    const int tot4  = B * 144;   // float4 units of output 0

    k_init<<<(tot8S + 255) / 256, 256, 0, stream>>>(Sb, (const float4*)noisy, tot8S);
    k_zero<<<(21 * RSL + 127) / 128, 128, 0, stream>>>(red, 21 * RSL);
    // NOTE: uv is NOT zeroed — step 0 has alpha == 0 (red slot 0 zeroed), so
    // u = v = 0 * uv regardless of poison (0xAAAA bf16 is a denormal, not NaN).
    k_wt<<<(HID * INF + 255) / 256, 256, 0, stream>>>(W1, Wt1, INF, HID, HID * INF);
    k_wt<<<(HID * HID + 255) / 256, 256, 0, stream>>>(W2, Wt2, HID, HID, HID * HID);
    k_wt<<<(OUTF * HID + 255) / 256, 256, 0, stream>>>(W3, Wt3, HID, OUTF, OUTF * HID);

    const int gfb = (tot24 + 255) / 256;     // 1536 blocks
    const int g1  = (B / 32) * 2;            // 1024 blocks (NB=2)
    const int g2  = (B / 32) * 2;            // 1024 blocks (NB=2)
    const int g3  = (B / 32) * 9;            // 4608 blocks (NB=9)

    for (int n = 0; n < TS; ++n) {
        float an = (float)n / ((float)n + 3.0f);
        float* redprev = red + (size_t)n * RSL;      // alpha source (slot n)
        float* redcur  = red + (size_t)(n + 1) * RSL;
        k_fbs<<<gfb, 256, 0, stream>>>(Sb, uv, redprev, redcur, an, tot24);
        k_gemm<128, true,  false, true, 2><<<g1, 256, 0, stream>>>(Sb, Wt1, b1, h1, INF, HID, nullptr);
        k_gemm<128, true,  false, true, 2><<<g2, 256, 0, stream>>>(h1, Wt2, b2, h2, HID, HID, nullptr);
        k_gemm<64,  false, true,  true, 9><<<g3, 256, 0, stream>>>(h2, Wt3, b3, uv, HID, OUTF, redcur + 1024);
    }
    k_finish<<<(tot4 + 255) / 256, 256, 0, stream>>>(Sb, (float4*)p_out,
                                                     red, res_out, tot4);
}

// Round 16
// 2089.471 us; speedup vs baseline: 2.8593x; 1.0853x over previous
//
#include <hip/hip_runtime.h>
#include <math.h>

constexpr int SVEC = 576;    // N_CH * 64
constexpr int INF  = 2304;   // 4 * SVEC
constexpr int HID  = 256;
constexpr int OUTF = 1152;   // 2 * SVEC
constexpr int TS   = 20;
// red slot layout (line-spread buckets, 1 bucket = 1 cache line):
//   r[b] at b*16, d[b] at 512+b*16, q[b] at 1024+b*16, b in 0..31
constexpr int RSL  = 1536;   // floats per step slot (6 KB)

// ---------- helpers ----------------------------------------------------------
__device__ __forceinline__ ushort f2bf(float f) {    // RNE f32->bf16
    union { float f; unsigned u; } a; a.f = f;
    unsigned r = a.u + 0x7fff + ((a.u >> 16) & 1);
    return (ushort)(r >> 16);
}
__device__ __forceinline__ float bf2f(ushort b) {
    union { unsigned u; float f; } a; a.u = ((unsigned)b) << 16;
    return a.f;
}

__device__ __forceinline__ void gload_lds16(const void* g, void* l) {
    __builtin_amdgcn_global_load_lds(
        (const __attribute__((address_space(1))) void*)g,
        (__attribute__((address_space(3))) void*)l, 16, 0, 0);
}

typedef short  s16x8 __attribute__((ext_vector_type(8)));
typedef float  f32x4 __attribute__((ext_vector_type(4)));

// ---------- init: Sb(bf16) = [x|p|y|z] all = [noisy, 0...] -------------------
__global__ __launch_bounds__(256) void k_init(ushort* __restrict__ Sb,
                                              const float4* __restrict__ noisy4,
                                              int tot8) {
    int i = blockIdx.x * 256 + threadIdx.x;
    if (i >= tot8) return;
    int sample = i / 288;
    int j = i - sample * 288;       // slot within sample
    int jc = j % 72;                // slot within chunk
    s16x8 o = (s16x8){0,0,0,0,0,0,0,0};
    if (jc < 8) {                   // first 64 elems = noisy
        float4 a = noisy4[sample * 16 + jc * 2];
        float4 b = noisy4[sample * 16 + jc * 2 + 1];
        ushort* u = (ushort*)&o;
        u[0]=f2bf(a.x); u[1]=f2bf(a.y); u[2]=f2bf(a.z); u[3]=f2bf(a.w);
        u[4]=f2bf(b.x); u[5]=f2bf(b.y); u[6]=f2bf(b.z); u[7]=f2bf(b.w);
    }
    *(s16x8*)&Sb[(size_t)i * 8] = o;
}

__global__ __launch_bounds__(128) void k_zero(float* __restrict__ p, int n) {
    int i = blockIdx.x * 128 + threadIdx.x;
    if (i < n) p[i] = 0.f;
}

// ---------- weight transpose + bf16 convert: Wt[n*K+k] = W[k*N+n] ------------
__global__ __launch_bounds__(256) void k_wt(const float* __restrict__ W,
                                            ushort* __restrict__ Wt,
                                            int K, int N, int total) {
    int i = blockIdx.x * 256 + threadIdx.x;
    if (i >= total) return;
    int n = i / K, k = i - n * K;
    Wt[i] = f2bf(W[(size_t)k * N + n]);
}

// ---------- elementwise FBS (in-place on bf16 Sb); 24 elems per thread -------
// Barrier-free; inline per-wave alpha from prev slot's line-spread d/q buckets;
// per-wave r/d atomics to line-spread buckets.
__global__ __launch_bounds__(256) void k_fbs(ushort* __restrict__ Sb,
                                             const ushort* __restrict__ uv,
                                             const float* __restrict__ redprev,
                                             float* __restrict__ redcur,
                                             float an, int tot24 /* B*24 */) {
    const int lane = threadIdx.x & 63, wave = threadIdx.x >> 6;
    // ---- inline alpha: lanes 0..31 read d buckets, 32..63 read q buckets
    float av = (lane < 32) ? redprev[512 + lane * 16]
                           : redprev[1024 + (lane - 32) * 16];
    #pragma unroll
    for (int off = 16; off > 0; off >>= 1) av += __shfl_down(av, off);
    float dsum = __shfl(av, 0), qsum = __shfl(av, 32);
    const float al = sqrtf(fminf(0.99f * fmaxf(dsum, 0.f) /
                                 (1.5f * qsum + 1e-12f), 1.f));

    int i = blockIdx.x * 256 + threadIdx.x;
    float r = 0.f, d = 0.f;
    if (i < tot24) {
        int sample = i / 24;
        int j24 = (i - sample * 24) * 24;        // elem offset within chunk
        size_t sb = (size_t)sample * INF + j24;
        size_t ub = (size_t)sample * OUTF + j24;
        s16x8 x8[3], p8[3], y8[3], z8[3], u8[3], v8[3];
        #pragma unroll
        for (int g = 0; g < 3; ++g) x8[g] = *(const s16x8*)(Sb + sb + g * 8);
        #pragma unroll
        for (int g = 0; g < 3; ++g) p8[g] = *(const s16x8*)(Sb + sb + 576 + g * 8);
        #pragma unroll
        for (int g = 0; g < 3; ++g) y8[g] = *(const s16x8*)(Sb + sb + 1152 + g * 8);
        #pragma unroll
        for (int g = 0; g < 3; ++g) z8[g] = *(const s16x8*)(Sb + sb + 1728 + g * 8);
        #pragma unroll
        for (int g = 0; g < 3; ++g) u8[g] = *(const s16x8*)(uv + ub + g * 8);
        #pragma unroll
        for (int g = 0; g < 3; ++g) v8[g] = *(const s16x8*)(uv + ub + 576 + g * 8);
        s16x8 xo[3], po[3], yo[3], zo[3];
        #pragma unroll
        for (int g = 0; g < 3; ++g) {
            const ushort* X = (const ushort*)&x8[g]; const ushort* P = (const ushort*)&p8[g];
            const ushort* Y = (const ushort*)&y8[g]; const ushort* Z = (const ushort*)&z8[g];
            const ushort* U = (const ushort*)&u8[g]; const ushort* V = (const ushort*)&v8[g];
            ushort* XO = (ushort*)&xo[g]; ushort* PO = (ushort*)&po[g];
            ushort* YO = (ushort*)&yo[g]; ushort* ZO = (ushort*)&zo[g];
            #pragma unroll
            for (int c = 0; c < 8; ++c) {
                float x = bf2f(X[c]), p = bf2f(P[c]);
                float yv = bf2f(Y[c]), zv = bf2f(Z[c]);
                float u = al * bf2f(U[c]), v = al * bf2f(V[c]);
                float y  = x + an * (yv - x) + u;
                float dz = an * (zv - p);
                float z  = x + an * (p - x) + dz + u + v;
                float zm = z - y;
                float t  = fabsf(zm) - 0.1f;
                float pr = (t > 0.f) ? copysignf(t, zm) : 0.f;
                float xn = x + (pr - z) + dz;
                XO[c] = f2bf(xn); PO[c] = f2bf(pr); YO[c] = f2bf(y); ZO[c] = f2bf(z);
                float e1 = pr - y; r += e1 * e1;
                float e2 = xn - z; d += e2 * e2;
            }
        }
        #pragma unroll
        for (int g = 0; g < 3; ++g) *(s16x8*)(Sb + sb + g * 8)        = xo[g];
        #pragma unroll
        for (int g = 0; g < 3; ++g) *(s16x8*)(Sb + sb + 576 + g * 8)  = po[g];
        #pragma unroll
        for (int g = 0; g < 3; ++g) *(s16x8*)(Sb + sb + 1152 + g * 8) = yo[g];
        #pragma unroll
        for (int g = 0; g < 3; ++g) *(s16x8*)(Sb + sb + 1728 + g * 8) = zo[g];
    }
    #pragma unroll
    for (int off = 32; off > 0; off >>= 1) {
        r += __shfl_down(r, off);
        d += __shfl_down(d, off);
    }
    if (lane == 0) {
        int bk = ((blockIdx.x << 2) | wave) & 31;
        atomicAdd(&redcur[bk * 16],       r);
        atomicAdd(&redcur[512 + bk * 16], d);
    }
}

// ---------- bf16 MFMA GEMM: C[M,N] = A[M,K] @ Wt[N,K]^T + bias ---------------
// 256 thr = 4 waves (each: 32 cols x 32*MI rows), tile (32*MI)x128, BK templ.
// MI m-subtiles amortize the staged B-tile (halves L2 B-restaging at MI=2).
// LDS XOR swizzle: slot row*CPB+cs stores global chunk cs^(row&(CPB-1)).
template <int BK, int MI, bool RELU, bool QACC, bool BF16OUT, int NB>
__global__ __launch_bounds__(256) void k_gemm(const ushort* __restrict__ A,
                                              const ushort* __restrict__ Wt,
                                              const float* __restrict__ bias,
                                              void* __restrict__ Cout,
                                              int K, int N,
                                              float* __restrict__ qbuck) {
    constexpr int MR = 32 * MI;              // rows per block
    __shared__ ushort As[MR * BK];
    __shared__ ushort Bs[128 * BK];
    const int tid = threadIdx.x;
    const int bx = blockIdx.x;
    const int m0 = (bx / NB) * MR;
    const int n0 = (bx % NB) * 128;
    const int wave = tid >> 6, lane = tid & 63;
    const int wn = wave * 32;
    const int lm = lane & 15, quad = lane >> 4;
    constexpr int CPB = BK / 8;              // 16B chunks per row
    constexpr int SWZ = CPB - 1;

    f32x4 acc[2 * MI][2];
    #pragma unroll
    for (int i = 0; i < 2 * MI; ++i)
        #pragma unroll
        for (int j = 0; j < 2; ++j) acc[i][j] = (f32x4){0.f, 0.f, 0.f, 0.f};

    for (int k0 = 0; k0 < K; k0 += BK) {
        #pragma unroll
        for (int c = tid; c < MR * CPB; c += 256) {      // A: MR rows
            int row = c / CPB, cs = c % CPB;
            int src = cs ^ (row & SWZ);
            gload_lds16(A + (size_t)(m0 + row) * K + k0 + src * 8, &As[c * 8]);
        }
        #pragma unroll
        for (int c = tid; c < 128 * CPB; c += 256) {     // B: 128 rows
            int row = c / CPB, cs = c % CPB;
            int src = cs ^ (row & SWZ);
            gload_lds16(Wt + (size_t)(n0 + row) * K + k0 + src * 8, &Bs[c * 8]);
        }
        __syncthreads();
        #pragma unroll
        for (int kk = 0; kk < BK; kk += 32) {
            s16x8 af[2 * MI], bfr[2];
            #pragma unroll
            for (int i = 0; i < 2 * MI; ++i) {
                int row = i * 16 + lm;
                int ch = ((kk >> 3) + quad) ^ (row & SWZ);
                af[i] = *(const s16x8*)&As[(row * CPB + ch) * 8];
            }
            #pragma unroll
            for (int j = 0; j < 2; ++j) {
                int row = wn + j * 16 + lm;
                int ch = ((kk >> 3) + quad) ^ (row & SWZ);
                bfr[j] = *(const s16x8*)&Bs[(row * CPB + ch) * 8];
            }
            #pragma unroll
            for (int i = 0; i < 2 * MI; ++i)
                #pragma unroll
                for (int j = 0; j < 2; ++j)
                    acc[i][j] = __builtin_amdgcn_mfma_f32_16x16x32_bf16(af[i], bfr[j], acc[i][j], 0, 0, 0);
        }
        __syncthreads();
    }

    float q = 0.f;
    #pragma unroll
    for (int j = 0; j < 2; ++j) {
        int col = n0 + wn + j * 16 + lm;
        float bb = bias[col];
        #pragma unroll
        for (int i = 0; i < 2 * MI; ++i) {
            #pragma unroll
            for (int rr = 0; rr < 4; ++rr) {
                int row = m0 + i * 16 + quad * 4 + rr;
                float c = acc[i][j][rr] + bb;
                if (RELU) c = fmaxf(c, 0.f);
                if (QACC) q += c * c;
                if (BF16OUT) ((ushort*)Cout)[(size_t)row * N + col] = f2bf(c);
                else         ((float*)Cout)[(size_t)row * N + col] = c;
            }
        }
    }
    if (QACC) {
        #pragma unroll
        for (int off = 32; off > 0; off >>= 1) q += __shfl_down(q, off);
        __shared__ float sq[4];
        if (lane == 0) sq[wave] = q;
        __syncthreads();
        if (tid == 0)
            atomicAdd(&qbuck[(bx & 31) * 16], sq[0] + sq[1] + sq[2] + sq[3]);
    }
}

// ---------- finish: p_final (bf16->f32) ; block 0 folds residuals ------------
__global__ __launch_bounds__(256) void k_finish(const ushort* __restrict__ Sb,
                                                float4* __restrict__ out4,
                                                const float* __restrict__ red,
                                                float* __restrict__ res_out,
                                                int total4 /* B*144 */) {
    int i = blockIdx.x * 256 + threadIdx.x;
    if (blockIdx.x == 0 && threadIdx.x < TS) {
        const float* rb = red + (size_t)(threadIdx.x + 1) * RSL;
        float s = 0.f;
        #pragma unroll
        for (int c = 0; c < 32; ++c) s += rb[c * 16];
        res_out[threadIdx.x] = sqrtf(s + 1e-12f);
    }
    if (i >= total4) return;
    int sample = i / 144;
    int j = i - sample * 144;
    const ushort* p = Sb + (size_t)sample * INF + 576 + j * 4;
    float4 o;
    o.x = bf2f(p[0]); o.y = bf2f(p[1]); o.z = bf2f(p[2]); o.w = bf2f(p[3]);
    out4[i] = o;
}

extern "C" void kernel_launch(void* const* d_in, const int* in_sizes, int n_in,
                              void* d_out, int out_size, void* d_ws, size_t ws_size,
                              hipStream_t stream) {
    const float* noisy = (const float*)d_in[0];
    const float* W1 = (const float*)d_in[1];
    const float* b1 = (const float*)d_in[2];
    const float* W2 = (const float*)d_in[3];
    const float* b2 = (const float*)d_in[4];
    const float* W3 = (const float*)d_in[5];
    const float* b3 = (const float*)d_in[6];
    const int B = in_sizes[0] / 64;   // 16384

    // workspace layout (~132 MB)
    ushort* Sb  = (ushort*)d_ws;                        // [B,2304] bf16
    ushort* uv  = Sb + (size_t)B * INF;                 // [B,1152] bf16
    ushort* h1  = uv + (size_t)B * OUTF;                // [B,256]  bf16
    ushort* h2  = h1 + (size_t)B * HID;                 // [B,256]  bf16
    ushort* Wt1 = h2 + (size_t)B * HID;                 // [256,2304] bf16
    ushort* Wt2 = Wt1 + (size_t)HID * INF;              // [256,256]  bf16
    ushort* Wt3 = Wt2 + (size_t)HID * HID;              // [1152,256] bf16
    // 64B-align red so each 16-float bucket sits on its own cache line
    float*  red = (float*)((((uintptr_t)(Wt3 + (size_t)OUTF * HID)) + 63) & ~(uintptr_t)63);

    float* p_out   = (float*)d_out;                     // [B,576]
    float* res_out = p_out + (size_t)B * SVEC;          // [20]

    const int tot8S = B * 288;   // s16x8 slots in Sb
    const int tot24 = B * 24;    // 24-elem groups per chunk
    const int tot4  = B * 144;   // float4 units of output 0

    k_init<<<(tot8S + 255) / 256, 256, 0, stream>>>(Sb, (const float4*)noisy, tot8S);
    k_zero<<<(21 * RSL + 127) / 128, 128, 0, stream>>>(red, 21 * RSL);
    // NOTE: uv is NOT zeroed — step 0 has alpha == 0 (red slot 0 zeroed), so
    // u = v = 0 * uv regardless of poison (0xAAAA bf16 is a denormal, not NaN).
    k_wt<<<(HID * INF + 255) / 256, 256, 0, stream>>>(W1, Wt1, INF, HID, HID * INF);
    k_wt<<<(HID * HID + 255) / 256, 256, 0, stream>>>(W2, Wt2, HID, HID, HID * HID);
    k_wt<<<(OUTF * HID + 255) / 256, 256, 0, stream>>>(W3, Wt3, HID, OUTF, OUTF * HID);

    const int gfb = (tot24 + 255) / 256;     // 1536 blocks
    const int g1  = (B / 64) * 2;            // 512 blocks  (MI=2, NB=2)
    const int g2  = (B / 64) * 2;            // 512 blocks  (MI=2, NB=2)
    const int g3  = (B / 64) * 9;            // 2304 blocks (MI=2, NB=9)

    for (int n = 0; n < TS; ++n) {
        float an = (float)n / ((float)n + 3.0f);
        float* redprev = red + (size_t)n * RSL;      // alpha source (slot n)
        float* redcur  = red + (size_t)(n + 1) * RSL;
        k_fbs<<<gfb, 256, 0, stream>>>(Sb, uv, redprev, redcur, an, tot24);
        k_gemm<128, 2, true,  false, true, 2><<<g1, 256, 0, stream>>>(Sb, Wt1, b1, h1, INF, HID, nullptr);
        k_gemm<128, 2, true,  false, true, 2><<<g2, 256, 0, stream>>>(h1, Wt2, b2, h2, HID, HID, nullptr);
        k_gemm<64,  2, false, true,  true, 9><<<g3, 256, 0, stream>>>(h2, Wt3, b3, uv, HID, OUTF, redcur + 1024);
    }
    k_finish<<<(tot4 + 255) / 256, 256, 0, stream>>>(Sb, (float4*)p_out,
                                                     red, res_out, tot4);
}

// Round 17
// 1976.157 us; speedup vs baseline: 3.0233x; 1.0573x over previous
//
#include <hip/hip_runtime.h>
#include <math.h>

constexpr int SVEC = 576;    // N_CH * 64
constexpr int INF  = 2304;   // 4 * SVEC
constexpr int HID  = 256;
constexpr int OUTF = 1152;   // 2 * SVEC
constexpr int TS   = 20;
// red slot layout (line-spread buckets, 1 bucket = 1 cache line):
//   r[b] at b*16, d[b] at 512+b*16, q[b] at 1024+b*16, b in 0..31
constexpr int RSL  = 1536;   // floats per step slot (6 KB)

// ---------- helpers ----------------------------------------------------------
__device__ __forceinline__ ushort f2bf(float f) {    // RNE f32->bf16
    union { float f; unsigned u; } a; a.f = f;
    unsigned r = a.u + 0x7fff + ((a.u >> 16) & 1);
    return (ushort)(r >> 16);
}
__device__ __forceinline__ float bf2f(ushort b) {
    union { unsigned u; float f; } a; a.u = ((unsigned)b) << 16;
    return a.f;
}

__device__ __forceinline__ void gload_lds16(const void* g, void* l) {
    __builtin_amdgcn_global_load_lds(
        (const __attribute__((address_space(1))) void*)g,
        (__attribute__((address_space(3))) void*)l, 16, 0, 0);
}

typedef short  s16x8 __attribute__((ext_vector_type(8)));
typedef float  f32x4 __attribute__((ext_vector_type(4)));

// ---------- init: Sb(bf16) = [x|p|y|z] all = [noisy, 0...] -------------------
__global__ __launch_bounds__(256) void k_init(ushort* __restrict__ Sb,
                                              const float4* __restrict__ noisy4,
                                              int tot8) {
    int i = blockIdx.x * 256 + threadIdx.x;
    if (i >= tot8) return;
    int sample = i / 288;
    int j = i - sample * 288;       // slot within sample
    int jc = j % 72;                // slot within chunk
    s16x8 o = (s16x8){0,0,0,0,0,0,0,0};
    if (jc < 8) {                   // first 64 elems = noisy
        float4 a = noisy4[sample * 16 + jc * 2];
        float4 b = noisy4[sample * 16 + jc * 2 + 1];
        ushort* u = (ushort*)&o;
        u[0]=f2bf(a.x); u[1]=f2bf(a.y); u[2]=f2bf(a.z); u[3]=f2bf(a.w);
        u[4]=f2bf(b.x); u[5]=f2bf(b.y); u[6]=f2bf(b.z); u[7]=f2bf(b.w);
    }
    *(s16x8*)&Sb[(size_t)i * 8] = o;
}

__global__ __launch_bounds__(128) void k_zero(float* __restrict__ p, int n) {
    int i = blockIdx.x * 128 + threadIdx.x;
    if (i < n) p[i] = 0.f;
}

// ---------- weight transpose + bf16 convert: Wt[n*K+k] = W[k*N+n] ------------
__global__ __launch_bounds__(256) void k_wt(const float* __restrict__ W,
                                            ushort* __restrict__ Wt,
                                            int K, int N, int total) {
    int i = blockIdx.x * 256 + threadIdx.x;
    if (i >= total) return;
    int n = i / K, k = i - n * K;
    Wt[i] = f2bf(W[(size_t)k * N + n]);
}

// ---------- elementwise FBS (in-place on bf16 Sb); 24 elems per thread -------
// Lane-interleaved: iteration g covers a contiguous 2048-elem slab with
// e = blockBase + g*2048 + tid*8, so every 16B access is 1KB/wave coalesced.
// Barrier-free; inline per-wave alpha; per-wave r/d atomics (line-spread).
__global__ __launch_bounds__(256) void k_fbs(ushort* __restrict__ Sb,
                                             const ushort* __restrict__ uv,
                                             const float* __restrict__ redprev,
                                             float* __restrict__ redcur,
                                             float an, int totE /* B*576 */) {
    const int lane = threadIdx.x & 63, wave = threadIdx.x >> 6;
    // ---- inline alpha: lanes 0..31 read d buckets, 32..63 read q buckets
    float av = (lane < 32) ? redprev[512 + lane * 16]
                           : redprev[1024 + (lane - 32) * 16];
    #pragma unroll
    for (int off = 16; off > 0; off >>= 1) av += __shfl_down(av, off);
    float dsum = __shfl(av, 0), qsum = __shfl(av, 32);
    const float al = sqrtf(fminf(0.99f * fmaxf(dsum, 0.f) /
                                 (1.5f * qsum + 1e-12f), 1.f));

    const int eb = blockIdx.x * 6144 + threadIdx.x * 8;  // elem idx, g stride 2048
    float r = 0.f, d = 0.f;
    size_t sbase[3], ubase[3];
    bool act[3];
    #pragma unroll
    for (int g = 0; g < 3; ++g) {
        int e = eb + g * 2048;
        act[g] = (e < totE);
        int sample = e / SVEC;               // 8 | 576 -> group stays in-sample
        int j = e - sample * SVEC;
        sbase[g] = (size_t)sample * INF + j;
        ubase[g] = (size_t)sample * OUTF + j;
    }
    s16x8 x8[3], p8[3], y8[3], z8[3], u8[3], v8[3];
    #pragma unroll
    for (int g = 0; g < 3; ++g) if (act[g]) x8[g] = *(const s16x8*)(Sb + sbase[g]);
    #pragma unroll
    for (int g = 0; g < 3; ++g) if (act[g]) p8[g] = *(const s16x8*)(Sb + sbase[g] + 576);
    #pragma unroll
    for (int g = 0; g < 3; ++g) if (act[g]) y8[g] = *(const s16x8*)(Sb + sbase[g] + 1152);
    #pragma unroll
    for (int g = 0; g < 3; ++g) if (act[g]) z8[g] = *(const s16x8*)(Sb + sbase[g] + 1728);
    #pragma unroll
    for (int g = 0; g < 3; ++g) if (act[g]) u8[g] = *(const s16x8*)(uv + ubase[g]);
    #pragma unroll
    for (int g = 0; g < 3; ++g) if (act[g]) v8[g] = *(const s16x8*)(uv + ubase[g] + 576);
    s16x8 xo[3], po[3], yo[3], zo[3];
    #pragma unroll
    for (int g = 0; g < 3; ++g) {
        if (!act[g]) continue;
        const ushort* X = (const ushort*)&x8[g]; const ushort* P = (const ushort*)&p8[g];
        const ushort* Y = (const ushort*)&y8[g]; const ushort* Z = (const ushort*)&z8[g];
        const ushort* U = (const ushort*)&u8[g]; const ushort* V = (const ushort*)&v8[g];
        ushort* XO = (ushort*)&xo[g]; ushort* PO = (ushort*)&po[g];
        ushort* YO = (ushort*)&yo[g]; ushort* ZO = (ushort*)&zo[g];
        #pragma unroll
        for (int c = 0; c < 8; ++c) {
            float x = bf2f(X[c]), p = bf2f(P[c]);
            float yv = bf2f(Y[c]), zv = bf2f(Z[c]);
            float u = al * bf2f(U[c]), v = al * bf2f(V[c]);
            float y  = x + an * (yv - x) + u;
            float dz = an * (zv - p);
            float z  = x + an * (p - x) + dz + u + v;
            float zm = z - y;
            float t  = fabsf(zm) - 0.1f;
            float pr = (t > 0.f) ? copysignf(t, zm) : 0.f;
            float xn = x + (pr - z) + dz;
            XO[c] = f2bf(xn); PO[c] = f2bf(pr); YO[c] = f2bf(y); ZO[c] = f2bf(z);
            float e1 = pr - y; r += e1 * e1;
            float e2 = xn - z; d += e2 * e2;
        }
    }
    #pragma unroll
    for (int g = 0; g < 3; ++g) if (act[g]) *(s16x8*)(Sb + sbase[g])        = xo[g];
    #pragma unroll
    for (int g = 0; g < 3; ++g) if (act[g]) *(s16x8*)(Sb + sbase[g] + 576)  = po[g];
    #pragma unroll
    for (int g = 0; g < 3; ++g) if (act[g]) *(s16x8*)(Sb + sbase[g] + 1152) = yo[g];
    #pragma unroll
    for (int g = 0; g < 3; ++g) if (act[g]) *(s16x8*)(Sb + sbase[g] + 1728) = zo[g];

    #pragma unroll
    for (int off = 32; off > 0; off >>= 1) {
        r += __shfl_down(r, off);
        d += __shfl_down(d, off);
    }
    if (lane == 0) {
        int bk = ((blockIdx.x << 2) | wave) & 31;
        atomicAdd(&redcur[bk * 16],       r);
        atomicAdd(&redcur[512 + bk * 16], d);
    }
}

// ---------- bf16 MFMA GEMM: C[M,N] = A[M,K] @ Wt[N,K]^T + bias ---------------
// 256 thr = 4 waves (each: 32 cols x 32*MI rows), tile (32*MI)x128, BK templ.
// MI m-subtiles amortize the staged B-tile (halves L2 B-restaging at MI=2).
// LDS XOR swizzle: slot row*CPB+cs stores global chunk cs^(row&(CPB-1)).
template <int BK, int MI, bool RELU, bool QACC, bool BF16OUT, int NB>
__global__ __launch_bounds__(256) void k_gemm(const ushort* __restrict__ A,
                                              const ushort* __restrict__ Wt,
                                              const float* __restrict__ bias,
                                              void* __restrict__ Cout,
                                              int K, int N,
                                              float* __restrict__ qbuck) {
    constexpr int MR = 32 * MI;              // rows per block
    __shared__ ushort As[MR * BK];
    __shared__ ushort Bs[128 * BK];
    const int tid = threadIdx.x;
    const int bx = blockIdx.x;
    const int m0 = (bx / NB) * MR;
    const int n0 = (bx % NB) * 128;
    const int wave = tid >> 6, lane = tid & 63;
    const int wn = wave * 32;
    const int lm = lane & 15, quad = lane >> 4;
    constexpr int CPB = BK / 8;              // 16B chunks per row
    constexpr int SWZ = CPB - 1;

    f32x4 acc[2 * MI][2];
    #pragma unroll
    for (int i = 0; i < 2 * MI; ++i)
        #pragma unroll
        for (int j = 0; j < 2; ++j) acc[i][j] = (f32x4){0.f, 0.f, 0.f, 0.f};

    for (int k0 = 0; k0 < K; k0 += BK) {
        #pragma unroll
        for (int c = tid; c < MR * CPB; c += 256) {      // A: MR rows
            int row = c / CPB, cs = c % CPB;
            int src = cs ^ (row & SWZ);
            gload_lds16(A + (size_t)(m0 + row) * K + k0 + src * 8, &As[c * 8]);
        }
        #pragma unroll
        for (int c = tid; c < 128 * CPB; c += 256) {     // B: 128 rows
            int row = c / CPB, cs = c % CPB;
            int src = cs ^ (row & SWZ);
            gload_lds16(Wt + (size_t)(n0 + row) * K + k0 + src * 8, &Bs[c * 8]);
        }
        __syncthreads();
        #pragma unroll
        for (int kk = 0; kk < BK; kk += 32) {
            s16x8 af[2 * MI], bfr[2];
            #pragma unroll
            for (int i = 0; i < 2 * MI; ++i) {
                int row = i * 16 + lm;
                int ch = ((kk >> 3) + quad) ^ (row & SWZ);
                af[i] = *(const s16x8*)&As[(row * CPB + ch) * 8];
            }
            #pragma unroll
            for (int j = 0; j < 2; ++j) {
                int row = wn + j * 16 + lm;
                int ch = ((kk >> 3) + quad) ^ (row & SWZ);
                bfr[j] = *(const s16x8*)&Bs[(row * CPB + ch) * 8];
            }
            #pragma unroll
            for (int i = 0; i < 2 * MI; ++i)
                #pragma unroll
                for (int j = 0; j < 2; ++j)
                    acc[i][j] = __builtin_amdgcn_mfma_f32_16x16x32_bf16(af[i], bfr[j], acc[i][j], 0, 0, 0);
        }
        __syncthreads();
    }

    float q = 0.f;
    #pragma unroll
    for (int j = 0; j < 2; ++j) {
        int col = n0 + wn + j * 16 + lm;
        float bb = bias[col];
        #pragma unroll
        for (int i = 0; i < 2 * MI; ++i) {
            #pragma unroll
            for (int rr = 0; rr < 4; ++rr) {
                int row = m0 + i * 16 + quad * 4 + rr;
                float c = acc[i][j][rr] + bb;
                if (RELU) c = fmaxf(c, 0.f);
                if (QACC) q += c * c;
                if (BF16OUT) ((ushort*)Cout)[(size_t)row * N + col] = f2bf(c);
                else         ((float*)Cout)[(size_t)row * N + col] = c;
            }
        }
    }
    if (QACC) {
        #pragma unroll
        for (int off = 32; off > 0; off >>= 1) q += __shfl_down(q, off);
        __shared__ float sq[4];
        if (lane == 0) sq[wave] = q;
        __syncthreads();
        if (tid == 0)
            atomicAdd(&qbuck[(bx & 31) * 16], sq[0] + sq[1] + sq[2] + sq[3]);
    }
}

// ---------- finish: p_final (bf16->f32) ; block 0 folds residuals ------------
__global__ __launch_bounds__(256) void k_finish(const ushort* __restrict__ Sb,
                                                float4* __restrict__ out4,
                                                const float* __restrict__ red,
                                                float* __restrict__ res_out,
                                                int total4 /* B*144 */) {
    int i = blockIdx.x * 256 + threadIdx.x;
    if (blockIdx.x == 0 && threadIdx.x < TS) {
        const float* rb = red + (size_t)(threadIdx.x + 1) * RSL;
        float s = 0.f;
        #pragma unroll
        for (int c = 0; c < 32; ++c) s += rb[c * 16];
        res_out[threadIdx.x] = sqrtf(s + 1e-12f);
    }
    if (i >= total4) return;
    int sample = i / 144;
    int j = i - sample * 144;
    const ushort* p = Sb + (size_t)sample * INF + 576 + j * 4;
    float4 o;
    o.x = bf2f(p[0]); o.y = bf2f(p[1]); o.z = bf2f(p[2]); o.w = bf2f(p[3]);
    out4[i] = o;
}

extern "C" void kernel_launch(void* const* d_in, const int* in_sizes, int n_in,
                              void* d_out, int out_size, void* d_ws, size_t ws_size,
                              hipStream_t stream) {
    const float* noisy = (const float*)d_in[0];
    const float* W1 = (const float*)d_in[1];
    const float* b1 = (const float*)d_in[2];
    const float* W2 = (const float*)d_in[3];
    const float* b2 = (const float*)d_in[4];
    const float* W3 = (const float*)d_in[5];
    const float* b3 = (const float*)d_in[6];
    const int B = in_sizes[0] / 64;   // 16384

    // workspace layout (~132 MB)
    ushort* Sb  = (ushort*)d_ws;                        // [B,2304] bf16
    ushort* uv  = Sb + (size_t)B * INF;                 // [B,1152] bf16
    ushort* h1  = uv + (size_t)B * OUTF;                // [B,256]  bf16
    ushort* h2  = h1 + (size_t)B * HID;                 // [B,256]  bf16
    ushort* Wt1 = h2 + (size_t)B * HID;                 // [256,2304] bf16
    ushort* Wt2 = Wt1 + (size_t)HID * INF;              // [256,256]  bf16
    ushort* Wt3 = Wt2 + (size_t)HID * HID;              // [1152,256] bf16
    // 64B-align red so each 16-float bucket sits on its own cache line
    float*  red = (float*)((((uintptr_t)(Wt3 + (size_t)OUTF * HID)) + 63) & ~(uintptr_t)63);

    float* p_out   = (float*)d_out;                     // [B,576]
    float* res_out = p_out + (size_t)B * SVEC;          // [20]

    const int tot8S = B * 288;   // s16x8 slots in Sb
    const int totE  = B * SVEC;  // elems per chunk stream
    const int tot4  = B * 144;   // float4 units of output 0

    k_init<<<(tot8S + 255) / 256, 256, 0, stream>>>(Sb, (const float4*)noisy, tot8S);
    k_zero<<<(21 * RSL + 127) / 128, 128, 0, stream>>>(red, 21 * RSL);
    // NOTE: uv is NOT zeroed — step 0 has alpha == 0 (red slot 0 zeroed), so
    // u = v = 0 * uv regardless of poison (0xAAAA bf16 is a denormal, not NaN).
    k_wt<<<(HID * INF + 255) / 256, 256, 0, stream>>>(W1, Wt1, INF, HID, HID * INF);
    k_wt<<<(HID * HID + 255) / 256, 256, 0, stream>>>(W2, Wt2, HID, HID, HID * HID);
    k_wt<<<(OUTF * HID + 255) / 256, 256, 0, stream>>>(W3, Wt3, HID, OUTF, OUTF * HID);

    const int gfb = (totE + 6143) / 6144;    // 1536 blocks
    const int g1  = (B / 64) * 2;            // 512 blocks  (MI=2, NB=2)
    const int g2  = (B / 64) * 2;            // 512 blocks  (MI=2, NB=2)
    const int g3  = (B / 64) * 9;            // 2304 blocks (MI=2, NB=9)

    for (int n = 0; n < TS; ++n) {
        float an = (float)n / ((float)n + 3.0f);
        float* redprev = red + (size_t)n * RSL;      // alpha source (slot n)
        float* redcur  = red + (size_t)(n + 1) * RSL;
        k_fbs<<<gfb, 256, 0, stream>>>(Sb, uv, redprev, redcur, an, totE);
        k_gemm<128, 2, true,  false, true, 2><<<g1, 256, 0, stream>>>(Sb, Wt1, b1, h1, INF, HID, nullptr);
        k_gemm<128, 2, true,  false, true, 2><<<g2, 256, 0, stream>>>(h1, Wt2, b2, h2, HID, HID, nullptr);
        k_gemm<64,  2, false, true,  true, 9><<<g3, 256, 0, stream>>>(h2, Wt3, b3, uv, HID, OUTF, redcur + 1024);
    }
    k_finish<<<(tot4 + 255) / 256, 256, 0, stream>>>(Sb, (float4*)p_out,
                                                     red, res_out, tot4);
}